// Round 4
// baseline (284.430 us; speedup 1.0000x reference)
//
#include <hip/hip_runtime.h>
#include <hip/hip_bf16.h>
#include <math.h>

// Problem constants (fixed by reference setup)
#define S_LEN   1024
#define BATCH   2
#define DMODEL  1024
#define NHEADS  16
#define HDIM    64
#define BHEADS  32          // BATCH*NHEADS
#define LP1     4           // 1 + L layers
#define ROWS_PL 2048        // S*B rows per layer

typedef __attribute__((ext_vector_type(8)))  short bf16x8;   // 8 bf16 = 4 VGPRs
typedef __attribute__((ext_vector_type(4)))  float f32x4;
typedef __attribute__((ext_vector_type(16))) float f32x16;

__device__ inline ushort bf16_rne(float a) {
    unsigned u = __float_as_uint(a);
    return (ushort)((u + 0x7FFFu + ((u >> 16) & 1u)) >> 16);
}
__device__ inline float bf16_up(ushort h) { return __uint_as_float(((unsigned)h) << 16); }
__device__ inline void split_bf16(float a, ushort &hi, ushort &lo) {
    hi = bf16_rne(a);
    lo = bf16_rne(a - bf16_up(hi));
}
// packed f32x2 -> bf16x2 (v_cvt_pk_bf16_f32)
__device__ inline uint pk_bf16(float a, float b) {
    float2 f; f.x = a; f.y = b;
    __hip_bfloat162 h = __float22bfloat162_rn(f);
    return *reinterpret_cast<uint*>(&h);
}
// raw v_exp_f32 (no denormal fixup path)
#if __has_builtin(__builtin_amdgcn_exp2f)
__device__ inline float fast_exp2(float x) { return __builtin_amdgcn_exp2f(x); }
#else
__device__ inline float fast_exp2(float x) { return exp2f(x); }
#endif

// v_permlane32_swap_b32 a, b:  a[32:63] <- b[0:31] ; b[0:31] <- a[32:63]
// (verified on HW in rounds 2/3: passed with identical absmax)
__device__ inline void permswap(uint &a, uint &b) {
    asm("v_permlane32_swap_b32 %0, %1" : "+v"(a), "+v"(b));
}

// Async global->LDS, 16 B per lane. HW places lane i at lds_base + i*16.
__device__ inline void glds16(const ushort* g, ushort* l) {
    __builtin_amdgcn_global_load_lds(
        (const __attribute__((address_space(1))) void*)g,
        (__attribute__((address_space(3))) void*)l, 16, 0, 0);
}

// hd^-0.5 * log2(e), folded into the Q projection epilogue
#define SCLF 0.18033688011112042f

// ---------------------------------------------------------------------------
// One-shot pre-split: Xs = [x ; layer_outputs] -> hi bf16 plane;
// Wq/Wo -> hi+lo planes; Wk/Wv -> hi plane only (lo dropped: its contribution
// is below the bf16 rounding already applied to K/V outputs).
// ---------------------------------------------------------------------------
__global__ __launch_bounds__(256)
void presplit(const float* __restrict__ x, const float* __restrict__ lo,
              const float* __restrict__ Wq, const float* __restrict__ Wk,
              const float* __restrict__ Wv, const float* __restrict__ Wo,
              ushort* __restrict__ XsH, ushort* __restrict__ WH,
              ushort* __restrict__ WL)
{
    const int z = blockIdx.z;
    const float* src; ushort* dh; ushort* dl = nullptr; int n;
    if (z == 0)      { src = x;  dh = XsH;           n = 2097152; }
    else if (z == 1) { src = lo; dh = XsH + 2097152; n = 6291456; }
    else {
        const float* wsrc[4] = { Wq, Wk, Wv, Wo };
        src = wsrc[z - 2];
        dh = WH + (size_t)(z - 2) * 1048576;
        if (z == 2 || z == 5) dl = WL + (size_t)(z - 2) * 1048576;
        n = 1048576;
    }
    const int i = (blockIdx.x * 256 + threadIdx.x) * 8;
    if (i >= n) return;
    float v[8];
    *(float4*)&v[0] = *(const float4*)(src + i);
    *(float4*)&v[4] = *(const float4*)(src + i + 4);
    ushort h[8];
    #pragma unroll
    for (int j = 0; j < 8; ++j) h[j] = bf16_rne(v[j]);
    *(uint4*)(dh + i) = *(uint4*)h;
    if (dl) {
        ushort l[8];
        #pragma unroll
        for (int j = 0; j < 8; ++j) l[j] = bf16_rne(v[j] - bf16_up(h[j]));
        *(uint4*)(dl + i) = *(uint4*)l;
    }
}

// ---------------------------------------------------------------------------
// Q / O projection, glds staging with XOR chunk swizzle (lane i fetches
// chunk (i&3)^((i>>2)&3): same 64 B lines, bank-friendly frag reads).
// C[2048,1024] = A_hi @ (W_hi+W_lo)^T + bias. BM=BN=64, BK=32, 256 thr.
// MODE 0: scale by SCLF, split hi/lo planes at [b*16+h][s][e]  (Q)
// MODE 1: fp32 row-major out[m][n]                             (O)
// ---------------------------------------------------------------------------
template<int MODE>
__global__ __launch_bounds__(256)
void proj_g(const ushort* __restrict__ Abf,
            const ushort* __restrict__ Bhg, const ushort* __restrict__ Blg,
            const float* __restrict__ bias,
            float* __restrict__ outf, ushort* __restrict__ outh,
            ushort* __restrict__ outl)
{
    __shared__ ushort smem[3 * 2048];    // Ah, Bh, Bl: [64][32]
    ushort* Ah = smem;
    ushort* Bh = smem + 2048;
    ushort* Bl = smem + 4096;

    const int fid = blockIdx.x;
    const int nt = (fid & 7) * 2 + ((fid >> 3) & 1);
    const int mt = fid >> 4;
    const int m0 = mt * 64, n0 = nt * 64;

    const int t  = threadIdx.x;
    const int wv = t >> 6, lane = t & 63;
    const int quad = lane >> 4, r = lane & 15;
    const int wm = wv & 1, wn = wv >> 1;
    const int mBase = wm * 32, nBase = wn * 32;

    const int lrow = lane >> 2;
    const int lch  = ((lane & 3) ^ (lrow & 3)) * 8;      // XOR chunk swizzle
    const ushort* Asrc  = Abf + (size_t)(m0 + wv * 16 + lrow) * DMODEL + lch;
    const ushort* Bhsrc = Bhg + (size_t)(n0 + wv * 16 + lrow) * DMODEL + lch;
    const ushort* Blsrc = Blg + (size_t)(n0 + wv * 16 + lrow) * DMODEL + lch;
    ushort* lA  = Ah + wv * 512;
    ushort* lBh = Bh + wv * 512;
    ushort* lBl = Bl + wv * 512;

    const int q0x = (quad ^ (r & 3)) << 3;               // swizzled frag chunk
    f32x4 acc[2][2];
    #pragma unroll
    for (int i = 0; i < 2; ++i)
        #pragma unroll
        for (int j = 0; j < 2; ++j) acc[i][j] = (f32x4){0.f, 0.f, 0.f, 0.f};

    for (int k0 = 0; k0 < DMODEL; k0 += 32) {
        glds16(Asrc + k0, lA);
        glds16(Bhsrc + k0, lBh);
        glds16(Blsrc + k0, lBl);
        __syncthreads();   // drains vmcnt -> staged data visible
        bf16x8 fa[2], fbh[2], fbl[2];
        #pragma unroll
        for (int i = 0; i < 2; ++i)
            fa[i] = *(const bf16x8*)&Ah[(mBase + i * 16 + r) * 32 + q0x];
        #pragma unroll
        for (int j = 0; j < 2; ++j) {
            fbh[j] = *(const bf16x8*)&Bh[(nBase + j * 16 + r) * 32 + q0x];
            fbl[j] = *(const bf16x8*)&Bl[(nBase + j * 16 + r) * 32 + q0x];
        }
        #pragma unroll
        for (int i = 0; i < 2; ++i)
            #pragma unroll
            for (int j = 0; j < 2; ++j) {
                acc[i][j] = __builtin_amdgcn_mfma_f32_16x16x32_bf16(fa[i], fbh[j], acc[i][j], 0, 0, 0);
                acc[i][j] = __builtin_amdgcn_mfma_f32_16x16x32_bf16(fa[i], fbl[j], acc[i][j], 0, 0, 0);
            }
        __syncthreads();   // LDS consumed before next iteration's glds
    }

    const int cn = lane & 15;
    #pragma unroll
    for (int j = 0; j < 2; ++j) {
        const int n = n0 + nBase + j * 16 + cn;
        const float bv = bias[n];
        #pragma unroll
        for (int i = 0; i < 2; ++i) {
            const int mrow = m0 + mBase + i * 16 + quad * 4;
            #pragma unroll
            for (int g = 0; g < 4; ++g) {
                const int m = mrow + g;
                if (MODE == 1) {
                    outf[(size_t)m * DMODEL + n] = acc[i][j][g] + bv;
                } else {
                    const float val = (acc[i][j][g] + bv) * SCLF;   // fold attn scale
                    const int s = m >> 1, b = m & 1;
                    const int bh = b * 16 + (n >> 6), e = n & 63;
                    const size_t idx = (((size_t)bh * S_LEN) + s) * HDIM + e;
                    ushort hi, lov; split_bf16(val, hi, lov);
                    outh[idx] = hi; outl[idx] = lov;
                }
            }
        }
    }
}

// ---------------------------------------------------------------------------
// Fused K+V projection, glds staging, hi-only weights (2 B planes), XOR
// chunk swizzle. BM=64, BN=128, BK=32, 256 thr (2x2 waves). LDS 20 KB.
// K epilogue: hi plane at [l*32+b*16+h][s][e]
// V epilogue: hi plane at [l*32+b*16+h][e][s] via LDS transpose.
// ---------------------------------------------------------------------------
__global__ __launch_bounds__(256, 4)
void proj_kv(const ushort* __restrict__ XsH,
             const ushort* __restrict__ KWh, const ushort* __restrict__ VWh,
             const float* __restrict__ bk, const float* __restrict__ bv,
             ushort* __restrict__ kout, ushort* __restrict__ vout)
{
    __shared__ ushort smem[10240];       // Ah 64x32 + 2 planes 128x32 = 20 KB
    ushort* Ah = smem;                   // [64][32]
    ushort* Bp = smem + 2048;            // [plane][128][32]

    const int t  = threadIdx.x;
    const int m0 = blockIdx.y * 64, n0 = blockIdx.x * 128;
    const int lyr = m0 >> 11;

    const int wv = t >> 6, lane = t & 63;
    const int quad = lane >> 4, r = lane & 15;
    const int wm = wv & 1, wn = wv >> 1;
    const int mBase = wm * 32, nBase = wn * 64;

    const int lrow = lane >> 2;
    const int lch  = ((lane & 3) ^ (lrow & 3)) * 8;      // XOR chunk swizzle

    const ushort* Asrc = XsH + (size_t)(m0 + wv * 16 + lrow) * DMODEL + lch;
    const ushort* Bw[2] = { KWh, VWh };
    const ushort* Bsrc[2][2];
    #pragma unroll
    for (int p = 0; p < 2; ++p)
        #pragma unroll
        for (int seg = 0; seg < 2; ++seg)
            Bsrc[p][seg] = Bw[p] + (size_t)(n0 + wv * 32 + seg * 16 + lrow) * DMODEL + lch;

    const int q0x = (quad ^ (r & 3)) << 3;

    f32x4 aK[2][4], aV[2][4];
    #pragma unroll
    for (int i = 0; i < 2; ++i)
        #pragma unroll
        for (int j = 0; j < 4; ++j) {
            aK[i][j] = (f32x4){0.f, 0.f, 0.f, 0.f};
            aV[i][j] = (f32x4){0.f, 0.f, 0.f, 0.f};
        }

    for (int k0 = 0; k0 < DMODEL; k0 += 32) {
        glds16(Asrc + k0, Ah + wv * 512);
        #pragma unroll
        for (int p = 0; p < 2; ++p)
            #pragma unroll
            for (int seg = 0; seg < 2; ++seg)
                glds16(Bsrc[p][seg] + k0, Bp + p * 4096 + (wv * 2 + seg) * 512);
        __syncthreads();

        bf16x8 fa[2];
        #pragma unroll
        for (int i = 0; i < 2; ++i)
            fa[i] = *(const bf16x8*)&Ah[(mBase + i * 16 + r) * 32 + q0x];
        #pragma unroll
        for (int j = 0; j < 4; ++j) {
            const int off = (nBase + j * 16 + r) * 32 + q0x;
            const bf16x8 fkh = *(const bf16x8*)&Bp[off];
            const bf16x8 fvh = *(const bf16x8*)&Bp[4096 + off];
            #pragma unroll
            for (int i = 0; i < 2; ++i) {
                aK[i][j] = __builtin_amdgcn_mfma_f32_16x16x32_bf16(fa[i], fkh, aK[i][j], 0, 0, 0);
                aV[i][j] = __builtin_amdgcn_mfma_f32_16x16x32_bf16(fa[i], fvh, aV[i][j], 0, 0, 0);
            }
        }
        __syncthreads();
    }

    const int cn = lane & 15;

    // ---- K epilogue: hi plane, [l*32+b*16+h][s][e] ----
    #pragma unroll
    for (int j = 0; j < 4; ++j) {
        const int n = n0 + nBase + j * 16 + cn;
        const float bb = bk[n];
        #pragma unroll
        for (int i = 0; i < 2; ++i) {
            #pragma unroll
            for (int g = 0; g < 4; ++g) {
                const int m = m0 + mBase + i * 16 + quad * 4 + g;
                const int rem = m & 2047, s = rem >> 1, b = rem & 1;
                const int bh = lyr * 32 + b * 16 + (n >> 6);
                kout[(((size_t)bh * S_LEN) + s) * HDIM + (n & 63)] = bf16_rne(aK[i][j][g] + bb);
            }
        }
    }

    // ---- V epilogue: transpose via LDS, coalesced stores ----
    ushort* T = smem;   // [128][66] = 8448 ushorts <= 10240
    __syncthreads();
    #pragma unroll
    for (int j = 0; j < 4; ++j) {
        const int nloc = nBase + j * 16 + cn;
        const float bb = bv[n0 + nloc];
        #pragma unroll
        for (int i = 0; i < 2; ++i) {
            #pragma unroll
            for (int g = 0; g < 4; ++g) {
                const int mloc = mBase + i * 16 + quad * 4 + g;
                T[nloc * 66 + mloc] = bf16_rne(aV[i][j][g] + bb);
            }
        }
    }
    __syncthreads();
    {
        const int nloc = t >> 1, bsel = t & 1;
        const int n = n0 + nloc, h = n >> 6, e = n & 63;
        const int s0g = (m0 & 2047) >> 1;
        const int bhI = lyr * 32 + bsel * 16 + h;
        ushort* dst = vout + ((size_t)bhI * HDIM + e) * S_LEN + s0g;
        #pragma unroll
        for (int c = 0; c < 4; ++c) {
            ushort tmp[8];
            #pragma unroll
            for (int j = 0; j < 8; ++j)
                tmp[j] = T[nloc * 66 + 2 * (c * 8 + j) + bsel];
            *(uint4*)(dst + c * 8) = *(uint4*)tmp;
        }
    }
}

// ---------------------------------------------------------------------------
// MFMA flash attention, swapped-operand layout (zero LDS, zero barriers),
// u=2 query tiles per wave (64 q), SOFTWARE-PIPELINED:
//   body(kt) = { softmax(sa_kt) -> pf ; QK(kt+1) -> sa ; PV(pf, V_kt) }
// so the QK dependency chain of kt+1 completes under PV(kt) + softmax(kt+1)
// issue, and softmax VALU overlaps QK MFMA issue (separate pipes).
// Final iteration computes one wasted QK tile (branchless, ~2% extra MFMA).
// Grid 512, XCD-swizzled; 2 blocks/CU; VGPR budget ~240 (<=256 keeps
// 2 waves/SIMD, which is the grid-imposed cap anyway).
// ---------------------------------------------------------------------------
__global__ __launch_bounds__(256, 2)
void attn_mfma(const ushort* __restrict__ qhg, const ushort* __restrict__ qlg,
               const ushort* __restrict__ kh, const ushort* __restrict__ vth,
               const float* __restrict__ lwraw, float* __restrict__ part)
{
    const int t    = threadIdx.x;
    const int wv   = t >> 6, lane = t & 63;
    const int half = lane >> 5, lid = lane & 31;

    const int fid  = blockIdx.x;                 // 512 blocks
    const int xcd  = fid & 7, slot = fid >> 3;   // slot in [0,64)
    const int pair = xcd * 16 + (slot >> 2);     // 16 (bh,l) pairs per XCD
    const int qt   = slot & 3;                   // 4 q-tiles of 256 per pair
    const int bh   = pair & 31, l = pair >> 5;
    const int qbase = qt * 256 + wv * 64;        // wave owns 64 queries

    float wl;
    {
        float v[LP1], wm = -3.0e38f;
        #pragma unroll
        for (int i = 0; i < LP1; ++i) { v[i] = lwraw[i]; wm = fmaxf(wm, v[i]); }
        float ws = 0.f;
        #pragma unroll
        for (int i = 0; i < LP1; ++i) { v[i] = __expf(v[i] - wm); ws += v[i]; }
        wl = v[l] / ws;
    }

    // Q fragments (B-frag: lane owns query row qbase+u*32+lid, 8 dims/frag)
    bf16x8 qh[2][4], ql[2][4];
    #pragma unroll
    for (int u = 0; u < 2; ++u) {
        const size_t qoff = ((size_t)bh * S_LEN + qbase + u * 32 + lid) * HDIM + half * 8;
        #pragma unroll
        for (int es = 0; es < 4; ++es) {
            qh[u][es] = *(const bf16x8*)(qhg + qoff + es * 16);
            ql[u][es] = *(const bf16x8*)(qlg + qoff + es * 16);
        }
    }

    f32x16 o[2][2];
    #pragma unroll
    for (int u = 0; u < 2; ++u)
        #pragma unroll
        for (int dg = 0; dg < 2; ++dg)
            #pragma unroll
            for (int i = 0; i < 16; ++i) o[u][dg][i] = 0.f;
    float ls[2] = {0.f, 0.f};

    const size_t kvo = (size_t)(l * BHEADS + bh) * S_LEN * HDIM;
    const ushort* kbase = kh + kvo + (size_t)lid * HDIM + half * 8;
    const ushort* vbase = vth + kvo + (size_t)lid * S_LEN + half * 8;

    // ---- prologue: K(0) -> kb; sa = QK(K(0)); K(1) -> kn ----
    bf16x8 kb[4], kn[4];
    #pragma unroll
    for (int es = 0; es < 4; ++es)
        kb[es] = *(const bf16x8*)(kbase + es * 16);
    #pragma unroll
    for (int es = 0; es < 4; ++es)
        kn[es] = *(const bf16x8*)(kbase + (size_t)32 * HDIM + es * 16);

    f32x16 sa[2];
    #pragma unroll
    for (int u = 0; u < 2; ++u)
        #pragma unroll
        for (int i = 0; i < 16; ++i) sa[u][i] = 0.f;
    #pragma unroll
    for (int es = 0; es < 4; ++es)
        #pragma unroll
        for (int u = 0; u < 2; ++u) {
            sa[u] = __builtin_amdgcn_mfma_f32_32x32x16_bf16(kb[es], qh[u][es], sa[u], 0, 0, 0);
            sa[u] = __builtin_amdgcn_mfma_f32_32x32x16_bf16(kb[es], ql[u][es], sa[u], 0, 0, 0);
        }

    for (int kt = 0; kt < 32; ++kt) {
        // ---- V(kt) loads: issued early, consumed by PV at body end ----
        bf16x8 vb[2][2];
        {
            const ushort* vp = vbase + kt * 32;
            #pragma unroll
            for (int ks = 0; ks < 2; ++ks)
                #pragma unroll
                for (int dg = 0; dg < 2; ++dg)
                    vb[ks][dg] = *(const bf16x8*)(vp + (size_t)dg * (32 * S_LEN) + ks * 16);
        }

        // ---- softmax(sa of kt) -> pf[2][2], ls; sa dead afterwards ----
        // sa[u] = S^T[k][q]: lane owns col q, reg r -> k=(r&3)+8*(r>>2)+4*half
        bf16x8 pf[2][2];
        #pragma unroll
        for (int ks = 0; ks < 2; ++ks) {
            #pragma unroll
            for (int u = 0; u < 2; ++u) {
                const float p0 = fast_exp2(sa[u][8 * ks + 0]);
                const float p1 = fast_exp2(sa[u][8 * ks + 1]);
                const float p2 = fast_exp2(sa[u][8 * ks + 2]);
                const float p3 = fast_exp2(sa[u][8 * ks + 3]);
                const float p4 = fast_exp2(sa[u][8 * ks + 4]);
                const float p5 = fast_exp2(sa[u][8 * ks + 5]);
                const float p6 = fast_exp2(sa[u][8 * ks + 6]);
                const float p7 = fast_exp2(sa[u][8 * ks + 7]);
                ls[u] += ((p0 + p1) + (p2 + p3)) + ((p4 + p5) + (p6 + p7));

                // Own regs (local k within the 16-key group):
                //   half=0: a0={0,1} a1={2,3} b0={8,9}  b1={10,11}
                //   half=1: a0={4,5} a1={6,7} b0={12,13} b1={14,15}
                // Lane needs k = half*8 + 0..7 of column q=lid.
                uint a0 = pk_bf16(p0, p1);
                uint a1 = pk_bf16(p2, p3);
                uint b0 = pk_bf16(p4, p5);
                uint b1 = pk_bf16(p6, p7);
                // a[32:63] <- b[0:31]; b[0:31] <- a[32:63]:
                //   a0 -> half0:{0,1}  half1:{8,9}   = W0
                //   b0 -> half0:{4,5}  half1:{12,13} = W2
                permswap(a0, b0);
                permswap(a1, b1);            // a1 = W1, b1 = W3
                union { uint w[4]; bf16x8 v; } pu;
                pu.w[0] = a0; pu.w[1] = a1; pu.w[2] = b0; pu.w[3] = b1;
                pf[ks][u] = pu.v;
            }
        }

        // ---- advance K: kb <- kn, prefetch K(kt+2) ----
        #pragma unroll
        for (int es = 0; es < 4; ++es) kb[es] = kn[es];
        {
            const ushort* kp = kbase + (size_t)((kt + 2) & 31) * 32 * HDIM;
            #pragma unroll
            for (int es = 0; es < 4; ++es) kn[es] = *(const bf16x8*)(kp + es * 16);
        }

        // ---- QK(kt+1) -> sa (on kt=31 computes an unused wrapped tile) ----
        #pragma unroll
        for (int u = 0; u < 2; ++u)
            #pragma unroll
            for (int i = 0; i < 16; ++i) sa[u][i] = 0.f;
        __builtin_amdgcn_s_setprio(1);
        #pragma unroll
        for (int es = 0; es < 4; ++es)
            #pragma unroll
            for (int u = 0; u < 2; ++u) {
                sa[u] = __builtin_amdgcn_mfma_f32_32x32x16_bf16(kb[es], qh[u][es], sa[u], 0, 0, 0);
                sa[u] = __builtin_amdgcn_mfma_f32_32x32x16_bf16(kb[es], ql[u][es], sa[u], 0, 0, 0);
            }
        __builtin_amdgcn_s_setprio(0);

        // ---- PV(kt): o += V^T(kt) x P^T(kt) ----
        __builtin_amdgcn_s_setprio(1);
        #pragma unroll
        for (int ks = 0; ks < 2; ++ks)
            #pragma unroll
            for (int dg = 0; dg < 2; ++dg)
                #pragma unroll
                for (int u = 0; u < 2; ++u)
                    o[u][dg] = __builtin_amdgcn_mfma_f32_32x32x16_bf16(vb[ks][dg], pf[ks][u], o[u][dg], 0, 0, 0);
        __builtin_amdgcn_s_setprio(0);
    }

    // ---- epilogue: combine half-lane partial sums, scale, store O^T ----
    const int b = bh >> 4, hh = bh & 15;
    #pragma unroll
    for (int u = 0; u < 2; ++u) {
        float lsv = ls[u];
        lsv += __shfl_xor(lsv, 32);
        const float sc = wl / lsv;
        const int q = qbase + u * 32 + lid;
        float* pb = part + (size_t)l * (ROWS_PL * DMODEL)
                  + ((size_t)q * BATCH + b) * DMODEL + hh * HDIM;
        #pragma unroll
        for (int dg = 0; dg < 2; ++dg)
            #pragma unroll
            for (int rq = 0; rq < 4; ++rq) {
                float4 vv;
                vv.x = o[u][dg][rq * 4 + 0] * sc;
                vv.y = o[u][dg][rq * 4 + 1] * sc;
                vv.z = o[u][dg][rq * 4 + 2] * sc;
                vv.w = o[u][dg][rq * 4 + 3] * sc;
                *(float4*)(pb + dg * 32 + rq * 8 + half * 4) = vv;
            }
    }
}

// ---------------------------------------------------------------------------
// Sum the 4 layer partials -> bf16 hi plane for the O projection.
// ---------------------------------------------------------------------------
__global__ __launch_bounds__(256)
void sum_y(const float* __restrict__ part, ushort* __restrict__ YH)
{
    const int i = (blockIdx.x * 256 + threadIdx.x) * 8;
    float acc[8];
    #pragma unroll
    for (int c = 0; c < 2; ++c) {
        float4 s = *(const float4*)(part + i + c * 4);
        #pragma unroll
        for (int l = 1; l < LP1; ++l) {
            const float4 p = *(const float4*)(part + (size_t)l * 2097152 + i + c * 4);
            s.x += p.x; s.y += p.y; s.z += p.z; s.w += p.w;
        }
        acc[c * 4 + 0] = s.x; acc[c * 4 + 1] = s.y;
        acc[c * 4 + 2] = s.z; acc[c * 4 + 3] = s.w;
    }
    uint out[4];
    #pragma unroll
    for (int c = 0; c < 4; ++c) out[c] = pk_bf16(acc[c * 2], acc[c * 2 + 1]);
    *(uint4*)(YH + i) = *(uint4*)out;
}

// ---------------------------------------------------------------------------
extern "C" void kernel_launch(void* const* d_in, const int* in_sizes, int n_in,
                              void* d_out, int out_size, void* d_ws, size_t ws_size,
                              hipStream_t stream) {
    const float* x  = (const float*)d_in[0];
    const float* lo = (const float*)d_in[1];
    const float* Wq = (const float*)d_in[2];
    const float* bq = (const float*)d_in[3];
    const float* Wk = (const float*)d_in[4];
    const float* bk = (const float*)d_in[5];
    const float* Wv = (const float*)d_in[6];
    const float* bv = (const float*)d_in[7];
    const float* Wo = (const float*)d_in[8];
    const float* bo = (const float*)d_in[9];
    const float* lw = (const float*)d_in[10];
    float* out = (float*)d_out;

    char* ws = (char*)d_ws;
    ushort* XsH  = (ushort*)(ws);                          // 16,777,216 B
    ushort* WH   = (ushort*)(ws + 16777216);               //  8,388,608 B
    ushort* WL   = (ushort*)(ws + 25165824);               //  8,388,608 B (Wq/Wo only)
    ushort* qhb  = (ushort*)(ws + 33554432);               //  4,194,304 B
    ushort* qlb  = (ushort*)(ws + 37748736);               //  4,194,304 B
    ushort* khb  = (ushort*)(ws + 41943040);               // 16,777,216 B
    ushort* vthb = (ushort*)(ws + 58720256);               // 16,777,216 B
    float*  part = (float*)(ws + 75497472);                // 33,554,432 B
    ushort* YH   = (ushort*)(ws + 109051904);              //  4,194,304 B
    // total 113,246,208 B

    dim3 blk(256);
    // Xs -> hi plane; Wq/Wo -> hi+lo; Wk/Wv -> hi only
    presplit<<<dim3(3072, 1, 6), blk, 0, stream>>>(x, lo, Wq, Wk, Wv, Wo, XsH, WH, WL);
    // Q projection (glds): pre-scaled hi/lo planes [b*16+h][s][e]
    proj_g<0><<<dim3(512), blk, 0, stream>>>(XsH, WH, WL, bq, nullptr, qhb, qlb);
    // fused K+V projection (glds, hi-only weights)
    proj_kv<<<dim3(8, 128), blk, 0, stream>>>(XsH,
        WH + 1048576, WH + 2097152, bk, bv, khb, vthb);
    // attention: 512 XCD-swizzled blocks -> per-layer fp32 partials
    attn_mfma<<<dim3(512), blk, 0, stream>>>(qhb, qlb, khb, vthb, lw, part);
    // reduce 4 partials -> bf16 hi plane
    sum_y<<<dim3(1024), blk, 0, stream>>>(part, YH);
    // output projection (glds)
    proj_g<1><<<dim3(512), blk, 0, stream>>>(YH, WH + 3145728, WL + 3145728, bo, out, nullptr, nullptr);
}

// Round 5
// 259.001 us; speedup vs baseline: 1.0982x; 1.0982x over previous
//
#include <hip/hip_runtime.h>
#include <hip/hip_bf16.h>
#include <math.h>

// Problem constants (fixed by reference setup)
#define S_LEN   1024
#define BATCH   2
#define DMODEL  1024
#define NHEADS  16
#define HDIM    64
#define BHEADS  32          // BATCH*NHEADS
#define LP1     4           // 1 + L layers
#define ROWS_PL 2048        // S*B rows per layer

typedef __attribute__((ext_vector_type(8)))  short bf16x8;   // 8 bf16 = 4 VGPRs
typedef __attribute__((ext_vector_type(4)))  float f32x4;
typedef __attribute__((ext_vector_type(16))) float f32x16;

__device__ inline ushort bf16_rne(float a) {
    unsigned u = __float_as_uint(a);
    return (ushort)((u + 0x7FFFu + ((u >> 16) & 1u)) >> 16);
}
__device__ inline float bf16_up(ushort h) { return __uint_as_float(((unsigned)h) << 16); }
__device__ inline void split_bf16(float a, ushort &hi, ushort &lo) {
    hi = bf16_rne(a);
    lo = bf16_rne(a - bf16_up(hi));
}
// packed f32x2 -> bf16x2 (v_cvt_pk_bf16_f32)
__device__ inline uint pk_bf16(float a, float b) {
    float2 f; f.x = a; f.y = b;
    __hip_bfloat162 h = __float22bfloat162_rn(f);
    return *reinterpret_cast<uint*>(&h);
}
// raw v_exp_f32 (no denormal fixup path)
#if __has_builtin(__builtin_amdgcn_exp2f)
__device__ inline float fast_exp2(float x) { return __builtin_amdgcn_exp2f(x); }
#else
__device__ inline float fast_exp2(float x) { return exp2f(x); }
#endif

// v_permlane32_swap_b32 a, b:  a[32:63] <- b[0:31] ; b[0:31] <- a[32:63]
// (verified on HW in rounds 2/3/4: passed with identical absmax)
__device__ inline void permswap(uint &a, uint &b) {
    asm("v_permlane32_swap_b32 %0, %1" : "+v"(a), "+v"(b));
}

// Async global->LDS, 16 B per lane. HW places lane i at lds_base + i*16.
__device__ inline void glds16(const ushort* g, ushort* l) {
    __builtin_amdgcn_global_load_lds(
        (const __attribute__((address_space(1))) void*)g,
        (__attribute__((address_space(3))) void*)l, 16, 0, 0);
}

// hd^-0.5 * log2(e), folded into the Q projection epilogue
#define SCLF 0.18033688011112042f

// ---------------------------------------------------------------------------
// One-shot pre-split: Xs = [x ; layer_outputs] -> hi bf16 plane;
// Wq/Wo -> hi+lo planes; Wk/Wv -> hi plane only (lo dropped: its contribution
// is below the bf16 rounding already applied to K/V outputs).
// ---------------------------------------------------------------------------
__global__ __launch_bounds__(256)
void presplit(const float* __restrict__ x, const float* __restrict__ lo,
              const float* __restrict__ Wq, const float* __restrict__ Wk,
              const float* __restrict__ Wv, const float* __restrict__ Wo,
              ushort* __restrict__ XsH, ushort* __restrict__ WH,
              ushort* __restrict__ WL)
{
    const int z = blockIdx.z;
    const float* src; ushort* dh; ushort* dl = nullptr; int n;
    if (z == 0)      { src = x;  dh = XsH;           n = 2097152; }
    else if (z == 1) { src = lo; dh = XsH + 2097152; n = 6291456; }
    else {
        const float* wsrc[4] = { Wq, Wk, Wv, Wo };
        src = wsrc[z - 2];
        dh = WH + (size_t)(z - 2) * 1048576;
        if (z == 2 || z == 5) dl = WL + (size_t)(z - 2) * 1048576;
        n = 1048576;
    }
    const int i = (blockIdx.x * 256 + threadIdx.x) * 8;
    if (i >= n) return;
    float v[8];
    *(float4*)&v[0] = *(const float4*)(src + i);
    *(float4*)&v[4] = *(const float4*)(src + i + 4);
    ushort h[8];
    #pragma unroll
    for (int j = 0; j < 8; ++j) h[j] = bf16_rne(v[j]);
    *(uint4*)(dh + i) = *(uint4*)h;
    if (dl) {
        ushort l[8];
        #pragma unroll
        for (int j = 0; j < 8; ++j) l[j] = bf16_rne(v[j] - bf16_up(h[j]));
        *(uint4*)(dl + i) = *(uint4*)l;
    }
}

// ---------------------------------------------------------------------------
// Q / O projection, glds staging with XOR chunk swizzle (lane i fetches
// chunk (i&3)^((i>>2)&3): same 64 B lines, bank-friendly frag reads).
// C[2048,1024] = A_hi @ (W_hi+W_lo)^T + bias. BM=BN=64, BK=32, 256 thr.
// MODE 0: scale by SCLF, split hi/lo planes at [b*16+h][s][e]  (Q)
// MODE 1: fp32 row-major out[m][n]                             (O)
// ---------------------------------------------------------------------------
template<int MODE>
__global__ __launch_bounds__(256)
void proj_g(const ushort* __restrict__ Abf,
            const ushort* __restrict__ Bhg, const ushort* __restrict__ Blg,
            const float* __restrict__ bias,
            float* __restrict__ outf, ushort* __restrict__ outh,
            ushort* __restrict__ outl)
{
    __shared__ ushort smem[3 * 2048];    // Ah, Bh, Bl: [64][32]
    ushort* Ah = smem;
    ushort* Bh = smem + 2048;
    ushort* Bl = smem + 4096;

    const int fid = blockIdx.x;
    const int nt = (fid & 7) * 2 + ((fid >> 3) & 1);
    const int mt = fid >> 4;
    const int m0 = mt * 64, n0 = nt * 64;

    const int t  = threadIdx.x;
    const int wv = t >> 6, lane = t & 63;
    const int quad = lane >> 4, r = lane & 15;
    const int wm = wv & 1, wn = wv >> 1;
    const int mBase = wm * 32, nBase = wn * 32;

    const int lrow = lane >> 2;
    const int lch  = ((lane & 3) ^ (lrow & 3)) * 8;      // XOR chunk swizzle
    const ushort* Asrc  = Abf + (size_t)(m0 + wv * 16 + lrow) * DMODEL + lch;
    const ushort* Bhsrc = Bhg + (size_t)(n0 + wv * 16 + lrow) * DMODEL + lch;
    const ushort* Blsrc = Blg + (size_t)(n0 + wv * 16 + lrow) * DMODEL + lch;
    ushort* lA  = Ah + wv * 512;
    ushort* lBh = Bh + wv * 512;
    ushort* lBl = Bl + wv * 512;

    const int q0x = (quad ^ (r & 3)) << 3;               // swizzled frag chunk
    f32x4 acc[2][2];
    #pragma unroll
    for (int i = 0; i < 2; ++i)
        #pragma unroll
        for (int j = 0; j < 2; ++j) acc[i][j] = (f32x4){0.f, 0.f, 0.f, 0.f};

    for (int k0 = 0; k0 < DMODEL; k0 += 32) {
        glds16(Asrc + k0, lA);
        glds16(Bhsrc + k0, lBh);
        glds16(Blsrc + k0, lBl);
        __syncthreads();   // drains vmcnt -> staged data visible
        bf16x8 fa[2], fbh[2], fbl[2];
        #pragma unroll
        for (int i = 0; i < 2; ++i)
            fa[i] = *(const bf16x8*)&Ah[(mBase + i * 16 + r) * 32 + q0x];
        #pragma unroll
        for (int j = 0; j < 2; ++j) {
            fbh[j] = *(const bf16x8*)&Bh[(nBase + j * 16 + r) * 32 + q0x];
            fbl[j] = *(const bf16x8*)&Bl[(nBase + j * 16 + r) * 32 + q0x];
        }
        #pragma unroll
        for (int i = 0; i < 2; ++i)
            #pragma unroll
            for (int j = 0; j < 2; ++j) {
                acc[i][j] = __builtin_amdgcn_mfma_f32_16x16x32_bf16(fa[i], fbh[j], acc[i][j], 0, 0, 0);
                acc[i][j] = __builtin_amdgcn_mfma_f32_16x16x32_bf16(fa[i], fbl[j], acc[i][j], 0, 0, 0);
            }
        __syncthreads();   // LDS consumed before next iteration's glds
    }

    const int cn = lane & 15;
    #pragma unroll
    for (int j = 0; j < 2; ++j) {
        const int n = n0 + nBase + j * 16 + cn;
        const float bv = bias[n];
        #pragma unroll
        for (int i = 0; i < 2; ++i) {
            const int mrow = m0 + mBase + i * 16 + quad * 4;
            #pragma unroll
            for (int g = 0; g < 4; ++g) {
                const int m = mrow + g;
                if (MODE == 1) {
                    outf[(size_t)m * DMODEL + n] = acc[i][j][g] + bv;
                } else {
                    const float val = (acc[i][j][g] + bv) * SCLF;   // fold attn scale
                    const int s = m >> 1, b = m & 1;
                    const int bh = b * 16 + (n >> 6), e = n & 63;
                    const size_t idx = (((size_t)bh * S_LEN) + s) * HDIM + e;
                    ushort hi, lov; split_bf16(val, hi, lov);
                    outh[idx] = hi; outl[idx] = lov;
                }
            }
        }
    }
}

// ---------------------------------------------------------------------------
// Fused K+V projection, glds staging, hi-only weights (2 B planes), XOR
// chunk swizzle. BM=64, BN=128, BK=32, 256 thr (2x2 waves). LDS 20 KB.
// K epilogue: FRAGMENT-LINEAR layout for coalesced attn loads:
//   khb[bhI][kt][es][lane][8], lane = half*32 + (s&31),
//   element (key s, dim e): kt=s>>5, es=(e&63)>>4, half=(e>>3)&1, j=e&7.
// V epilogue: LDS transpose, then FRAGMENT-LINEAR:
//   vthb[bhI][kt][ks*2+dg][lane][8], lane = half*32 + (e&31),
//   element (key s, dim e): ks=(s>>4)&1, half=(s>>3)&1, j=s&7, dg=(e&63)>>5.
// ---------------------------------------------------------------------------
__global__ __launch_bounds__(256, 4)
void proj_kv(const ushort* __restrict__ XsH,
             const ushort* __restrict__ KWh, const ushort* __restrict__ VWh,
             const float* __restrict__ bk, const float* __restrict__ bv,
             ushort* __restrict__ kout, ushort* __restrict__ vout)
{
    __shared__ ushort smem[10240];       // Ah 64x32 + 2 planes 128x32 = 20 KB
    ushort* Ah = smem;                   // [64][32]
    ushort* Bp = smem + 2048;            // [plane][128][32]

    const int t  = threadIdx.x;
    const int m0 = blockIdx.y * 64, n0 = blockIdx.x * 128;
    const int lyr = m0 >> 11;

    const int wv = t >> 6, lane = t & 63;
    const int quad = lane >> 4, r = lane & 15;
    const int wm = wv & 1, wn = wv >> 1;
    const int mBase = wm * 32, nBase = wn * 64;

    const int lrow = lane >> 2;
    const int lch  = ((lane & 3) ^ (lrow & 3)) * 8;      // XOR chunk swizzle

    const ushort* Asrc = XsH + (size_t)(m0 + wv * 16 + lrow) * DMODEL + lch;
    const ushort* Bw[2] = { KWh, VWh };
    const ushort* Bsrc[2][2];
    #pragma unroll
    for (int p = 0; p < 2; ++p)
        #pragma unroll
        for (int seg = 0; seg < 2; ++seg)
            Bsrc[p][seg] = Bw[p] + (size_t)(n0 + wv * 32 + seg * 16 + lrow) * DMODEL + lch;

    const int q0x = (quad ^ (r & 3)) << 3;

    f32x4 aK[2][4], aV[2][4];
    #pragma unroll
    for (int i = 0; i < 2; ++i)
        #pragma unroll
        for (int j = 0; j < 4; ++j) {
            aK[i][j] = (f32x4){0.f, 0.f, 0.f, 0.f};
            aV[i][j] = (f32x4){0.f, 0.f, 0.f, 0.f};
        }

    for (int k0 = 0; k0 < DMODEL; k0 += 32) {
        glds16(Asrc + k0, Ah + wv * 512);
        #pragma unroll
        for (int p = 0; p < 2; ++p)
            #pragma unroll
            for (int seg = 0; seg < 2; ++seg)
                glds16(Bsrc[p][seg] + k0, Bp + p * 4096 + (wv * 2 + seg) * 512);
        __syncthreads();

        bf16x8 fa[2];
        #pragma unroll
        for (int i = 0; i < 2; ++i)
            fa[i] = *(const bf16x8*)&Ah[(mBase + i * 16 + r) * 32 + q0x];
        #pragma unroll
        for (int j = 0; j < 4; ++j) {
            const int off = (nBase + j * 16 + r) * 32 + q0x;
            const bf16x8 fkh = *(const bf16x8*)&Bp[off];
            const bf16x8 fvh = *(const bf16x8*)&Bp[4096 + off];
            #pragma unroll
            for (int i = 0; i < 2; ++i) {
                aK[i][j] = __builtin_amdgcn_mfma_f32_16x16x32_bf16(fa[i], fkh, aK[i][j], 0, 0, 0);
                aV[i][j] = __builtin_amdgcn_mfma_f32_16x16x32_bf16(fa[i], fvh, aV[i][j], 0, 0, 0);
            }
        }
        __syncthreads();
    }

    const int cn = lane & 15;

    // ---- K epilogue: fragment-linear [bhI][kt][es][lane][8] ----
    #pragma unroll
    for (int j = 0; j < 4; ++j) {
        const int n = n0 + nBase + j * 16 + cn;
        const float bb = bk[n];
        const int e    = n & 63;
        const int es_k = e >> 4, half_k = (e >> 3) & 1, j_k = e & 7;
        const int h    = n >> 6;
        #pragma unroll
        for (int i = 0; i < 2; ++i) {
            #pragma unroll
            for (int g = 0; g < 4; ++g) {
                const int m = m0 + mBase + i * 16 + quad * 4 + g;
                const int rem = m & 2047, s = rem >> 1, b = rem & 1;
                const int bhI = lyr * 32 + b * 16 + h;
                const int kt  = s >> 5;
                const int lnk = half_k * 32 + (s & 31);
                kout[(size_t)bhI * 65536 + (size_t)(kt * 4 + es_k) * 512 + lnk * 8 + j_k]
                    = bf16_rne(aK[i][j][g] + bb);
            }
        }
    }

    // ---- V epilogue: transpose via LDS, fragment-linear coalesced stores ----
    ushort* T = smem;   // [128][66] = 8448 ushorts <= 10240
    __syncthreads();
    #pragma unroll
    for (int j = 0; j < 4; ++j) {
        const int nloc = nBase + j * 16 + cn;
        const float bb = bv[n0 + nloc];
        #pragma unroll
        for (int i = 0; i < 2; ++i) {
            #pragma unroll
            for (int g = 0; g < 4; ++g) {
                const int mloc = mBase + i * 16 + quad * 4 + g;
                T[nloc * 66 + mloc] = bf16_rne(aV[i][j][g] + bb);
            }
        }
    }
    __syncthreads();
    {
        const int nloc = t >> 1, bsel = t & 1;
        const int n = n0 + nloc, h = n >> 6;
        const int e = n & 63;
        const int dg = e >> 5, lid_v = e & 31;
        const int s0g = (m0 & 2047) >> 1;          // multiple of 32
        const int kt  = s0g >> 5;
        const int bhI = lyr * 32 + bsel * 16 + h;
        ushort* dstb = vout + (size_t)bhI * 65536 + (size_t)kt * 2048;
        #pragma unroll
        for (int c = 0; c < 4; ++c) {
            ushort tmp[8];
            #pragma unroll
            for (int j = 0; j < 8; ++j)
                tmp[j] = T[nloc * 66 + 2 * (c * 8 + j) + bsel];
            // 8 consecutive keys s = s0g + c*8 + 0..7:
            //   ks = c>>1, half = c&1, j_v = 0..7 -> one contiguous uint4
            const int ks = c >> 1, hv = c & 1;
            *(uint4*)(dstb + (ks * 2 + dg) * 512 + (hv * 32 + lid_v) * 8) = *(uint4*)tmp;
        }
    }
}

// ---------------------------------------------------------------------------
// MFMA flash attention, swapped-operand layout (zero LDS, zero barriers),
// u=2 query tiles per wave (64 q), software-pipelined, FRAGMENT-LINEAR K/V:
// every K/V load is base + lane*16B -> one coalesced 1 KB burst per
// instruction (was a 32-cache-line gather at 128B/2KB lane stride; that
// scatter was the round-2..4 plateau at ~82 us / 26% MfmaUtil).
// Grid 512, XCD-swizzled; 2 blocks/CU.
// ---------------------------------------------------------------------------
__global__ __launch_bounds__(256, 2)
void attn_mfma(const ushort* __restrict__ qhg, const ushort* __restrict__ qlg,
               const ushort* __restrict__ kh, const ushort* __restrict__ vth,
               const float* __restrict__ lwraw, float* __restrict__ part)
{
    const int t    = threadIdx.x;
    const int wv   = t >> 6, lane = t & 63;
    const int half = lane >> 5, lid = lane & 31;

    const int fid  = blockIdx.x;                 // 512 blocks
    const int xcd  = fid & 7, slot = fid >> 3;   // slot in [0,64)
    const int pair = xcd * 16 + (slot >> 2);     // 16 (bh,l) pairs per XCD
    const int qt   = slot & 3;                   // 4 q-tiles of 256 per pair
    const int bh   = pair & 31, l = pair >> 5;
    const int qbase = qt * 256 + wv * 64;        // wave owns 64 queries

    float wl;
    {
        float v[LP1], wm = -3.0e38f;
        #pragma unroll
        for (int i = 0; i < LP1; ++i) { v[i] = lwraw[i]; wm = fmaxf(wm, v[i]); }
        float ws = 0.f;
        #pragma unroll
        for (int i = 0; i < LP1; ++i) { v[i] = __expf(v[i] - wm); ws += v[i]; }
        wl = v[l] / ws;
    }

    // Q fragments (B-frag: lane owns query row qbase+u*32+lid, 8 dims/frag)
    bf16x8 qh[2][4], ql[2][4];
    #pragma unroll
    for (int u = 0; u < 2; ++u) {
        const size_t qoff = ((size_t)bh * S_LEN + qbase + u * 32 + lid) * HDIM + half * 8;
        #pragma unroll
        for (int es = 0; es < 4; ++es) {
            qh[u][es] = *(const bf16x8*)(qhg + qoff + es * 16);
            ql[u][es] = *(const bf16x8*)(qlg + qoff + es * 16);
        }
    }

    f32x16 o[2][2];
    #pragma unroll
    for (int u = 0; u < 2; ++u)
        #pragma unroll
        for (int dg = 0; dg < 2; ++dg)
            #pragma unroll
            for (int i = 0; i < 16; ++i) o[u][dg][i] = 0.f;
    float ls[2] = {0.f, 0.f};

    // fragment-linear bases: every load below is base + lane*16B (coalesced)
    const size_t kvo = (size_t)(l * BHEADS + bh) * S_LEN * HDIM;
    const ushort* kfb = kh  + kvo + (size_t)lane * 8;
    const ushort* vfb = vth + kvo + (size_t)lane * 8;

    // ---- prologue: K(0) -> kb; sa = QK(K(0)); K(1) -> kn ----
    bf16x8 kb[4], kn[4];
    #pragma unroll
    for (int es = 0; es < 4; ++es)
        kb[es] = *(const bf16x8*)(kfb + es * 512);
    #pragma unroll
    for (int es = 0; es < 4; ++es)
        kn[es] = *(const bf16x8*)(kfb + 2048 + es * 512);

    f32x16 sa[2];
    #pragma unroll
    for (int u = 0; u < 2; ++u)
        #pragma unroll
        for (int i = 0; i < 16; ++i) sa[u][i] = 0.f;
    #pragma unroll
    for (int es = 0; es < 4; ++es)
        #pragma unroll
        for (int u = 0; u < 2; ++u) {
            sa[u] = __builtin_amdgcn_mfma_f32_32x32x16_bf16(kb[es], qh[u][es], sa[u], 0, 0, 0);
            sa[u] = __builtin_amdgcn_mfma_f32_32x32x16_bf16(kb[es], ql[u][es], sa[u], 0, 0, 0);
        }

    for (int kt = 0; kt < 32; ++kt) {
        // ---- V(kt) loads: coalesced, issued early, consumed by PV ----
        bf16x8 vb[2][2];
        {
            const ushort* vp = vfb + (size_t)kt * 2048;
            #pragma unroll
            for (int ks = 0; ks < 2; ++ks)
                #pragma unroll
                for (int dg = 0; dg < 2; ++dg)
                    vb[ks][dg] = *(const bf16x8*)(vp + (ks * 2 + dg) * 512);
        }

        // ---- softmax(sa of kt) -> pf[2][2], ls; sa dead afterwards ----
        // sa[u] = S^T[k][q]: lane owns col q, reg r -> k=(r&3)+8*(r>>2)+4*half
        bf16x8 pf[2][2];
        #pragma unroll
        for (int ks = 0; ks < 2; ++ks) {
            #pragma unroll
            for (int u = 0; u < 2; ++u) {
                const float p0 = fast_exp2(sa[u][8 * ks + 0]);
                const float p1 = fast_exp2(sa[u][8 * ks + 1]);
                const float p2 = fast_exp2(sa[u][8 * ks + 2]);
                const float p3 = fast_exp2(sa[u][8 * ks + 3]);
                const float p4 = fast_exp2(sa[u][8 * ks + 4]);
                const float p5 = fast_exp2(sa[u][8 * ks + 5]);
                const float p6 = fast_exp2(sa[u][8 * ks + 6]);
                const float p7 = fast_exp2(sa[u][8 * ks + 7]);
                ls[u] += ((p0 + p1) + (p2 + p3)) + ((p4 + p5) + (p6 + p7));

                // Own regs (local k within the 16-key group):
                //   half=0: a0={0,1} a1={2,3} b0={8,9}  b1={10,11}
                //   half=1: a0={4,5} a1={6,7} b0={12,13} b1={14,15}
                // Lane needs k = half*8 + 0..7 of column q=lid.
                uint a0 = pk_bf16(p0, p1);
                uint a1 = pk_bf16(p2, p3);
                uint b0 = pk_bf16(p4, p5);
                uint b1 = pk_bf16(p6, p7);
                // a[32:63] <- b[0:31]; b[0:31] <- a[32:63]:
                //   a0 -> half0:{0,1}  half1:{8,9}   = W0
                //   b0 -> half0:{4,5}  half1:{12,13} = W2
                permswap(a0, b0);
                permswap(a1, b1);            // a1 = W1, b1 = W3
                union { uint w[4]; bf16x8 v; } pu;
                pu.w[0] = a0; pu.w[1] = a1; pu.w[2] = b0; pu.w[3] = b1;
                pf[ks][u] = pu.v;
            }
        }

        // ---- advance K: kb <- kn, prefetch K(kt+2), coalesced ----
        #pragma unroll
        for (int es = 0; es < 4; ++es) kb[es] = kn[es];
        {
            const ushort* kp = kfb + (size_t)((kt + 2) & 31) * 2048;
            #pragma unroll
            for (int es = 0; es < 4; ++es) kn[es] = *(const bf16x8*)(kp + es * 512);
        }

        // ---- QK(kt+1) -> sa (on kt=31 computes an unused wrapped tile) ----
        #pragma unroll
        for (int u = 0; u < 2; ++u)
            #pragma unroll
            for (int i = 0; i < 16; ++i) sa[u][i] = 0.f;
        __builtin_amdgcn_s_setprio(1);
        #pragma unroll
        for (int es = 0; es < 4; ++es)
            #pragma unroll
            for (int u = 0; u < 2; ++u) {
                sa[u] = __builtin_amdgcn_mfma_f32_32x32x16_bf16(kb[es], qh[u][es], sa[u], 0, 0, 0);
                sa[u] = __builtin_amdgcn_mfma_f32_32x32x16_bf16(kb[es], ql[u][es], sa[u], 0, 0, 0);
            }
        __builtin_amdgcn_s_setprio(0);

        // ---- PV(kt): o += V^T(kt) x P^T(kt) ----
        __builtin_amdgcn_s_setprio(1);
        #pragma unroll
        for (int ks = 0; ks < 2; ++ks)
            #pragma unroll
            for (int dg = 0; dg < 2; ++dg)
                #pragma unroll
                for (int u = 0; u < 2; ++u)
                    o[u][dg] = __builtin_amdgcn_mfma_f32_32x32x16_bf16(vb[ks][dg], pf[ks][u], o[u][dg], 0, 0, 0);
        __builtin_amdgcn_s_setprio(0);
    }

    // ---- epilogue: combine half-lane partial sums, scale, store O^T ----
    const int b = bh >> 4, hh = bh & 15;
    #pragma unroll
    for (int u = 0; u < 2; ++u) {
        float lsv = ls[u];
        lsv += __shfl_xor(lsv, 32);
        const float sc = wl / lsv;
        const int q = qbase + u * 32 + lid;
        float* pb = part + (size_t)l * (ROWS_PL * DMODEL)
                  + ((size_t)q * BATCH + b) * DMODEL + hh * HDIM;
        #pragma unroll
        for (int dg = 0; dg < 2; ++dg)
            #pragma unroll
            for (int rq = 0; rq < 4; ++rq) {
                float4 vv;
                vv.x = o[u][dg][rq * 4 + 0] * sc;
                vv.y = o[u][dg][rq * 4 + 1] * sc;
                vv.z = o[u][dg][rq * 4 + 2] * sc;
                vv.w = o[u][dg][rq * 4 + 3] * sc;
                *(float4*)(pb + dg * 32 + rq * 8 + half * 4) = vv;
            }
    }
}

// ---------------------------------------------------------------------------
// Sum the 4 layer partials -> bf16 hi plane for the O projection.
// ---------------------------------------------------------------------------
__global__ __launch_bounds__(256)
void sum_y(const float* __restrict__ part, ushort* __restrict__ YH)
{
    const int i = (blockIdx.x * 256 + threadIdx.x) * 8;
    float acc[8];
    #pragma unroll
    for (int c = 0; c < 2; ++c) {
        float4 s = *(const float4*)(part + i + c * 4);
        #pragma unroll
        for (int l = 1; l < LP1; ++l) {
            const float4 p = *(const float4*)(part + (size_t)l * 2097152 + i + c * 4);
            s.x += p.x; s.y += p.y; s.z += p.z; s.w += p.w;
        }
        acc[c * 4 + 0] = s.x; acc[c * 4 + 1] = s.y;
        acc[c * 4 + 2] = s.z; acc[c * 4 + 3] = s.w;
    }
    uint out[4];
    #pragma unroll
    for (int c = 0; c < 4; ++c) out[c] = pk_bf16(acc[c * 2], acc[c * 2 + 1]);
    *(uint4*)(YH + i) = *(uint4*)out;
}

// ---------------------------------------------------------------------------
extern "C" void kernel_launch(void* const* d_in, const int* in_sizes, int n_in,
                              void* d_out, int out_size, void* d_ws, size_t ws_size,
                              hipStream_t stream) {
    const float* x  = (const float*)d_in[0];
    const float* lo = (const float*)d_in[1];
    const float* Wq = (const float*)d_in[2];
    const float* bq = (const float*)d_in[3];
    const float* Wk = (const float*)d_in[4];
    const float* bk = (const float*)d_in[5];
    const float* Wv = (const float*)d_in[6];
    const float* bv = (const float*)d_in[7];
    const float* Wo = (const float*)d_in[8];
    const float* bo = (const float*)d_in[9];
    const float* lw = (const float*)d_in[10];
    float* out = (float*)d_out;

    char* ws = (char*)d_ws;
    ushort* XsH  = (ushort*)(ws);                          // 16,777,216 B
    ushort* WH   = (ushort*)(ws + 16777216);               //  8,388,608 B
    ushort* WL   = (ushort*)(ws + 25165824);               //  8,388,608 B (Wq/Wo only)
    ushort* qhb  = (ushort*)(ws + 33554432);               //  4,194,304 B
    ushort* qlb  = (ushort*)(ws + 37748736);               //  4,194,304 B
    ushort* khb  = (ushort*)(ws + 41943040);               // 16,777,216 B
    ushort* vthb = (ushort*)(ws + 58720256);               // 16,777,216 B
    float*  part = (float*)(ws + 75497472);                // 33,554,432 B
    ushort* YH   = (ushort*)(ws + 109051904);              //  4,194,304 B
    // total 113,246,208 B

    dim3 blk(256);
    // Xs -> hi plane; Wq/Wo -> hi+lo; Wk/Wv -> hi only
    presplit<<<dim3(3072, 1, 6), blk, 0, stream>>>(x, lo, Wq, Wk, Wv, Wo, XsH, WH, WL);
    // Q projection (glds): pre-scaled hi/lo planes [b*16+h][s][e]
    proj_g<0><<<dim3(512), blk, 0, stream>>>(XsH, WH, WL, bq, nullptr, qhb, qlb);
    // fused K+V projection (glds, hi-only weights, fragment-linear outputs)
    proj_kv<<<dim3(8, 128), blk, 0, stream>>>(XsH,
        WH + 1048576, WH + 2097152, bk, bv, khb, vthb);
    // attention: 512 XCD-swizzled blocks -> per-layer fp32 partials
    attn_mfma<<<dim3(512), blk, 0, stream>>>(qhb, qlb, khb, vthb, lw, part);
    // reduce 4 partials -> bf16 hi plane
    sum_y<<<dim3(1024), blk, 0, stream>>>(part, YH);
    // output projection (glds)
    proj_g<1><<<dim3(512), blk, 0, stream>>>(YH, WH + 3145728, WL + 3145728, bo, out, nullptr, nullptr);
}

// Round 6
// 248.372 us; speedup vs baseline: 1.1452x; 1.0428x over previous
//
#include <hip/hip_runtime.h>
#include <hip/hip_bf16.h>
#include <math.h>

// Problem constants (fixed by reference setup)
#define S_LEN   1024
#define BATCH   2
#define DMODEL  1024
#define NHEADS  16
#define HDIM    64
#define BHEADS  32          // BATCH*NHEADS
#define LP1     4           // 1 + L layers
#define ROWS_PL 2048        // S*B rows per layer

typedef __attribute__((ext_vector_type(8)))  short bf16x8;   // 8 bf16 = 4 VGPRs
typedef __attribute__((ext_vector_type(4)))  float f32x4;
typedef __attribute__((ext_vector_type(16))) float f32x16;

__device__ inline ushort bf16_rne(float a) {
    unsigned u = __float_as_uint(a);
    return (ushort)((u + 0x7FFFu + ((u >> 16) & 1u)) >> 16);
}
__device__ inline float bf16_up(ushort h) { return __uint_as_float(((unsigned)h) << 16); }
__device__ inline void split_bf16(float a, ushort &hi, ushort &lo) {
    hi = bf16_rne(a);
    lo = bf16_rne(a - bf16_up(hi));
}
// packed f32x2 -> bf16x2 (v_cvt_pk_bf16_f32)
__device__ inline uint pk_bf16(float a, float b) {
    float2 f; f.x = a; f.y = b;
    __hip_bfloat162 h = __float22bfloat162_rn(f);
    return *reinterpret_cast<uint*>(&h);
}
// raw v_exp_f32 (no denormal fixup path)
#if __has_builtin(__builtin_amdgcn_exp2f)
__device__ inline float fast_exp2(float x) { return __builtin_amdgcn_exp2f(x); }
#else
__device__ inline float fast_exp2(float x) { return exp2f(x); }
#endif

// v_permlane32_swap_b32 a, b:  a[32:63] <- b[0:31] ; b[0:31] <- a[32:63]
// (verified on HW in rounds 2-5: passed with identical absmax)
__device__ inline void permswap(uint &a, uint &b) {
    asm("v_permlane32_swap_b32 %0, %1" : "+v"(a), "+v"(b));
}

// Async global->LDS, 16 B per lane. HW places lane i at lds_base + i*16.
__device__ inline void glds16(const ushort* g, ushort* l) {
    __builtin_amdgcn_global_load_lds(
        (const __attribute__((address_space(1))) void*)g,
        (__attribute__((address_space(3))) void*)l, 16, 0, 0);
}

// hd^-0.5 * log2(e), folded into the Q projection epilogue
#define SCLF 0.18033688011112042f

// ---------------------------------------------------------------------------
// One-shot pre-split: Xs = [x ; layer_outputs] -> hi bf16 plane;
// Wq/Wo -> hi+lo planes; Wk/Wv -> hi plane only (lo dropped: its contribution
// is below the bf16 rounding already applied to K/V outputs).
// ---------------------------------------------------------------------------
__global__ __launch_bounds__(256)
void presplit(const float* __restrict__ x, const float* __restrict__ lo,
              const float* __restrict__ Wq, const float* __restrict__ Wk,
              const float* __restrict__ Wv, const float* __restrict__ Wo,
              ushort* __restrict__ XsH, ushort* __restrict__ WH,
              ushort* __restrict__ WL)
{
    const int z = blockIdx.z;
    const float* src; ushort* dh; ushort* dl = nullptr; int n;
    if (z == 0)      { src = x;  dh = XsH;           n = 2097152; }
    else if (z == 1) { src = lo; dh = XsH + 2097152; n = 6291456; }
    else {
        const float* wsrc[4] = { Wq, Wk, Wv, Wo };
        src = wsrc[z - 2];
        dh = WH + (size_t)(z - 2) * 1048576;
        if (z == 2 || z == 5) dl = WL + (size_t)(z - 2) * 1048576;
        n = 1048576;
    }
    const int i = (blockIdx.x * 256 + threadIdx.x) * 8;
    if (i >= n) return;
    float v[8];
    *(float4*)&v[0] = *(const float4*)(src + i);
    *(float4*)&v[4] = *(const float4*)(src + i + 4);
    ushort h[8];
    #pragma unroll
    for (int j = 0; j < 8; ++j) h[j] = bf16_rne(v[j]);
    *(uint4*)(dh + i) = *(uint4*)h;
    if (dl) {
        ushort l[8];
        #pragma unroll
        for (int j = 0; j < 8; ++j) l[j] = bf16_rne(v[j] - bf16_up(h[j]));
        *(uint4*)(dl + i) = *(uint4*)l;
    }
}

// ---------------------------------------------------------------------------
// Q / O projection, glds staging, DOUBLE-BUFFERED: one barrier per K-step;
// tile k+1's global->LDS latency hides under tile k's MFMAs.
// XOR chunk swizzle on the staging source (bank-friendly frag reads).
// C[2048,1024] = A_hi @ (W_hi+W_lo)^T + bias. BM=BN=64, BK=32, 256 thr.
// MODE 0: scale by SCLF, split hi/lo planes at [b*16+h][s][e]  (Q)
// MODE 1: fp32 row-major out[m][n]                             (O)
// ---------------------------------------------------------------------------
template<int MODE>
__global__ __launch_bounds__(256)
void proj_g(const ushort* __restrict__ Abf,
            const ushort* __restrict__ Bhg, const ushort* __restrict__ Blg,
            const float* __restrict__ bias,
            float* __restrict__ outf, ushort* __restrict__ outh,
            ushort* __restrict__ outl)
{
    __shared__ ushort smem[2][3 * 2048];   // dbuf x {Ah, Bh, Bl}: 24 KB

    const int fid = blockIdx.x;
    const int nt = (fid & 7) * 2 + ((fid >> 3) & 1);
    const int mt = fid >> 4;
    const int m0 = mt * 64, n0 = nt * 64;

    const int t  = threadIdx.x;
    const int wv = t >> 6, lane = t & 63;
    const int quad = lane >> 4, r = lane & 15;
    const int wm = wv & 1, wn = wv >> 1;
    const int mBase = wm * 32, nBase = wn * 32;

    const int lrow = lane >> 2;
    const int lch  = ((lane & 3) ^ (lrow & 3)) * 8;      // XOR chunk swizzle
    const ushort* Asrc  = Abf + (size_t)(m0 + wv * 16 + lrow) * DMODEL + lch;
    const ushort* Bhsrc = Bhg + (size_t)(n0 + wv * 16 + lrow) * DMODEL + lch;
    const ushort* Blsrc = Blg + (size_t)(n0 + wv * 16 + lrow) * DMODEL + lch;

    const int q0x = (quad ^ (r & 3)) << 3;               // swizzled frag chunk
    f32x4 acc[2][2];
    #pragma unroll
    for (int i = 0; i < 2; ++i)
        #pragma unroll
        for (int j = 0; j < 2; ++j) acc[i][j] = (f32x4){0.f, 0.f, 0.f, 0.f};

    // prologue: stage tile 0 into buf 0
    glds16(Asrc,  smem[0]        + wv * 512);
    glds16(Bhsrc, smem[0] + 2048 + wv * 512);
    glds16(Blsrc, smem[0] + 4096 + wv * 512);

    for (int k = 0; k < 32; ++k) {
        const int cur = k & 1;
        __syncthreads();   // vmcnt drained: buf[cur] visible; prev reads done
        if (k + 1 < 32) {  // stage next tile into the other buffer
            const int off = (k + 1) * 32;
            glds16(Asrc  + off, smem[cur ^ 1]        + wv * 512);
            glds16(Bhsrc + off, smem[cur ^ 1] + 2048 + wv * 512);
            glds16(Blsrc + off, smem[cur ^ 1] + 4096 + wv * 512);
        }
        const ushort* Ah = smem[cur];
        const ushort* Bh = smem[cur] + 2048;
        const ushort* Bl = smem[cur] + 4096;
        bf16x8 fa[2], fbh[2], fbl[2];
        #pragma unroll
        for (int i = 0; i < 2; ++i)
            fa[i] = *(const bf16x8*)&Ah[(mBase + i * 16 + r) * 32 + q0x];
        #pragma unroll
        for (int j = 0; j < 2; ++j) {
            fbh[j] = *(const bf16x8*)&Bh[(nBase + j * 16 + r) * 32 + q0x];
            fbl[j] = *(const bf16x8*)&Bl[(nBase + j * 16 + r) * 32 + q0x];
        }
        #pragma unroll
        for (int i = 0; i < 2; ++i)
            #pragma unroll
            for (int j = 0; j < 2; ++j) {
                acc[i][j] = __builtin_amdgcn_mfma_f32_16x16x32_bf16(fa[i], fbh[j], acc[i][j], 0, 0, 0);
                acc[i][j] = __builtin_amdgcn_mfma_f32_16x16x32_bf16(fa[i], fbl[j], acc[i][j], 0, 0, 0);
            }
    }

    const int cn = lane & 15;
    #pragma unroll
    for (int j = 0; j < 2; ++j) {
        const int n = n0 + nBase + j * 16 + cn;
        const float bv = bias[n];
        #pragma unroll
        for (int i = 0; i < 2; ++i) {
            const int mrow = m0 + mBase + i * 16 + quad * 4;
            #pragma unroll
            for (int g = 0; g < 4; ++g) {
                const int m = mrow + g;
                if (MODE == 1) {
                    outf[(size_t)m * DMODEL + n] = acc[i][j][g] + bv;
                } else {
                    const float val = (acc[i][j][g] + bv) * SCLF;   // fold attn scale
                    const int s = m >> 1, b = m & 1;
                    const int bh = b * 16 + (n >> 6), e = n & 63;
                    const size_t idx = (((size_t)bh * S_LEN) + s) * HDIM + e;
                    ushort hi, lov; split_bf16(val, hi, lov);
                    outh[idx] = hi; outl[idx] = lov;
                }
            }
        }
    }
}

// ---------------------------------------------------------------------------
// Fused K+V projection, glds staging, DOUBLE-BUFFERED (one barrier/K-step),
// hi-only weights. BM=64, BN=128, BK=32, 256 thr (2x2 waves). LDS 40 KB.
// K epilogue: FRAGMENT-LINEAR layout for coalesced attn loads:
//   khb[bhI][kt][es][lane][8], lane = half*32 + (s&31).
// V epilogue: LDS transpose, then FRAGMENT-LINEAR:
//   vthb[bhI][kt][ks*2+dg][lane][8], lane = half*32 + (e&31).
// ---------------------------------------------------------------------------
__global__ __launch_bounds__(256, 4)
void proj_kv(const ushort* __restrict__ XsH,
             const ushort* __restrict__ KWh, const ushort* __restrict__ VWh,
             const float* __restrict__ bk, const float* __restrict__ bv,
             ushort* __restrict__ kout, ushort* __restrict__ vout)
{
    __shared__ ushort smem[2][10240];    // dbuf x {Ah 64x32, Bp 2x128x32} = 40 KB

    const int t  = threadIdx.x;
    const int m0 = blockIdx.y * 64, n0 = blockIdx.x * 128;
    const int lyr = m0 >> 11;

    const int wv = t >> 6, lane = t & 63;
    const int quad = lane >> 4, r = lane & 15;
    const int wm = wv & 1, wn = wv >> 1;
    const int mBase = wm * 32, nBase = wn * 64;

    const int lrow = lane >> 2;
    const int lch  = ((lane & 3) ^ (lrow & 3)) * 8;      // XOR chunk swizzle

    const ushort* Asrc = XsH + (size_t)(m0 + wv * 16 + lrow) * DMODEL + lch;
    const ushort* Bw[2] = { KWh, VWh };
    const ushort* Bsrc[2][2];
    #pragma unroll
    for (int p = 0; p < 2; ++p)
        #pragma unroll
        for (int seg = 0; seg < 2; ++seg)
            Bsrc[p][seg] = Bw[p] + (size_t)(n0 + wv * 32 + seg * 16 + lrow) * DMODEL + lch;

    const int q0x = (quad ^ (r & 3)) << 3;

    f32x4 aK[2][4], aV[2][4];
    #pragma unroll
    for (int i = 0; i < 2; ++i)
        #pragma unroll
        for (int j = 0; j < 4; ++j) {
            aK[i][j] = (f32x4){0.f, 0.f, 0.f, 0.f};
            aV[i][j] = (f32x4){0.f, 0.f, 0.f, 0.f};
        }

    // prologue: stage tile 0 into buf 0
    glds16(Asrc, smem[0] + wv * 512);
    #pragma unroll
    for (int p = 0; p < 2; ++p)
        #pragma unroll
        for (int seg = 0; seg < 2; ++seg)
            glds16(Bsrc[p][seg], smem[0] + 2048 + p * 4096 + (wv * 2 + seg) * 512);

    for (int k = 0; k < 32; ++k) {
        const int cur = k & 1;
        __syncthreads();   // vmcnt drained: buf[cur] visible; prev reads done
        if (k + 1 < 32) {
            const int off = (k + 1) * 32;
            glds16(Asrc + off, smem[cur ^ 1] + wv * 512);
            #pragma unroll
            for (int p = 0; p < 2; ++p)
                #pragma unroll
                for (int seg = 0; seg < 2; ++seg)
                    glds16(Bsrc[p][seg] + off,
                           smem[cur ^ 1] + 2048 + p * 4096 + (wv * 2 + seg) * 512);
        }
        const ushort* Ah = smem[cur];
        const ushort* Bp = smem[cur] + 2048;

        bf16x8 fa[2];
        #pragma unroll
        for (int i = 0; i < 2; ++i)
            fa[i] = *(const bf16x8*)&Ah[(mBase + i * 16 + r) * 32 + q0x];
        #pragma unroll
        for (int j = 0; j < 4; ++j) {
            const int off = (nBase + j * 16 + r) * 32 + q0x;
            const bf16x8 fkh = *(const bf16x8*)&Bp[off];
            const bf16x8 fvh = *(const bf16x8*)&Bp[4096 + off];
            #pragma unroll
            for (int i = 0; i < 2; ++i) {
                aK[i][j] = __builtin_amdgcn_mfma_f32_16x16x32_bf16(fa[i], fkh, aK[i][j], 0, 0, 0);
                aV[i][j] = __builtin_amdgcn_mfma_f32_16x16x32_bf16(fa[i], fvh, aV[i][j], 0, 0, 0);
            }
        }
    }

    const int cn = lane & 15;

    // ---- K epilogue: fragment-linear [bhI][kt][es][lane][8] ----
    #pragma unroll
    for (int j = 0; j < 4; ++j) {
        const int n = n0 + nBase + j * 16 + cn;
        const float bb = bk[n];
        const int e    = n & 63;
        const int es_k = e >> 4, half_k = (e >> 3) & 1, j_k = e & 7;
        const int h    = n >> 6;
        #pragma unroll
        for (int i = 0; i < 2; ++i) {
            #pragma unroll
            for (int g = 0; g < 4; ++g) {
                const int m = m0 + mBase + i * 16 + quad * 4 + g;
                const int rem = m & 2047, s = rem >> 1, b = rem & 1;
                const int bhI = lyr * 32 + b * 16 + h;
                const int kt  = s >> 5;
                const int lnk = half_k * 32 + (s & 31);
                kout[(size_t)bhI * 65536 + (size_t)(kt * 4 + es_k) * 512 + lnk * 8 + j_k]
                    = bf16_rne(aK[i][j][g] + bb);
            }
        }
    }

    // ---- V epilogue: transpose via LDS, fragment-linear coalesced stores ----
    ushort* T = smem[0];   // [128][66] = 8448 ushorts <= 10240
    __syncthreads();
    #pragma unroll
    for (int j = 0; j < 4; ++j) {
        const int nloc = nBase + j * 16 + cn;
        const float bb = bv[n0 + nloc];
        #pragma unroll
        for (int i = 0; i < 2; ++i) {
            #pragma unroll
            for (int g = 0; g < 4; ++g) {
                const int mloc = mBase + i * 16 + quad * 4 + g;
                T[nloc * 66 + mloc] = bf16_rne(aV[i][j][g] + bb);
            }
        }
    }
    __syncthreads();
    {
        const int nloc = t >> 1, bsel = t & 1;
        const int n = n0 + nloc, h = n >> 6;
        const int e = n & 63;
        const int dg = e >> 5, lid_v = e & 31;
        const int s0g = (m0 & 2047) >> 1;          // multiple of 32
        const int kt  = s0g >> 5;
        const int bhI = lyr * 32 + bsel * 16 + h;
        ushort* dstb = vout + (size_t)bhI * 65536 + (size_t)kt * 2048;
        #pragma unroll
        for (int c = 0; c < 4; ++c) {
            ushort tmp[8];
            #pragma unroll
            for (int j = 0; j < 8; ++j)
                tmp[j] = T[nloc * 66 + 2 * (c * 8 + j) + bsel];
            // 8 consecutive keys s = s0g + c*8 + 0..7:
            //   ks = c>>1, half = c&1, j_v = 0..7 -> one contiguous uint4
            const int ks = c >> 1, hv = c & 1;
            *(uint4*)(dstb + (ks * 2 + dg) * 512 + (hv * 32 + lid_v) * 8) = *(uint4*)tmp;
        }
    }
}

// ---------------------------------------------------------------------------
// MFMA flash attention, swapped-operand layout (zero LDS, zero barriers),
// u=2 query tiles per wave (64 q), software-pipelined, FRAGMENT-LINEAR K/V
// (coalesced base+lane*16B loads). QK chains seeded with a persistent zero
// C-vector (no per-iteration accumulator re-zeroing). Grid 512, XCD-swizzled.
// ---------------------------------------------------------------------------
__global__ __launch_bounds__(256, 2)
void attn_mfma(const ushort* __restrict__ qhg, const ushort* __restrict__ qlg,
               const ushort* __restrict__ kh, const ushort* __restrict__ vth,
               const float* __restrict__ lwraw, float* __restrict__ part)
{
    const int t    = threadIdx.x;
    const int wv   = t >> 6, lane = t & 63;
    const int half = lane >> 5, lid = lane & 31;

    const int fid  = blockIdx.x;                 // 512 blocks
    const int xcd  = fid & 7, slot = fid >> 3;   // slot in [0,64)
    const int pair = xcd * 16 + (slot >> 2);     // 16 (bh,l) pairs per XCD
    const int qt   = slot & 3;                   // 4 q-tiles of 256 per pair
    const int bh   = pair & 31, l = pair >> 5;
    const int qbase = qt * 256 + wv * 64;        // wave owns 64 queries

    float wl;
    {
        float v[LP1], wm = -3.0e38f;
        #pragma unroll
        for (int i = 0; i < LP1; ++i) { v[i] = lwraw[i]; wm = fmaxf(wm, v[i]); }
        float ws = 0.f;
        #pragma unroll
        for (int i = 0; i < LP1; ++i) { v[i] = __expf(v[i] - wm); ws += v[i]; }
        wl = v[l] / ws;
    }

    // Q fragments (B-frag: lane owns query row qbase+u*32+lid, 8 dims/frag)
    bf16x8 qh[2][4], ql[2][4];
    #pragma unroll
    for (int u = 0; u < 2; ++u) {
        const size_t qoff = ((size_t)bh * S_LEN + qbase + u * 32 + lid) * HDIM + half * 8;
        #pragma unroll
        for (int es = 0; es < 4; ++es) {
            qh[u][es] = *(const bf16x8*)(qhg + qoff + es * 16);
            ql[u][es] = *(const bf16x8*)(qlg + qoff + es * 16);
        }
    }

    f32x16 o[2][2];
    #pragma unroll
    for (int u = 0; u < 2; ++u)
        #pragma unroll
        for (int dg = 0; dg < 2; ++dg)
            #pragma unroll
            for (int i = 0; i < 16; ++i) o[u][dg][i] = 0.f;
    float ls[2] = {0.f, 0.f};

    // persistent zero C-operand: seeds each QK chain, never re-written
    f32x16 zf;
    #pragma unroll
    for (int i = 0; i < 16; ++i) zf[i] = 0.f;

    // fragment-linear bases: every load below is base + lane*16B (coalesced)
    const size_t kvo = (size_t)(l * BHEADS + bh) * S_LEN * HDIM;
    const ushort* kfb = kh  + kvo + (size_t)lane * 8;
    const ushort* vfb = vth + kvo + (size_t)lane * 8;

    // ---- prologue: K(0) -> kb; sa = QK(K(0)); K(1) -> kn ----
    bf16x8 kb[4], kn[4];
    #pragma unroll
    for (int es = 0; es < 4; ++es)
        kb[es] = *(const bf16x8*)(kfb + es * 512);
    #pragma unroll
    for (int es = 0; es < 4; ++es)
        kn[es] = *(const bf16x8*)(kfb + 2048 + es * 512);

    f32x16 sa[2];
    #pragma unroll
    for (int es = 0; es < 4; ++es)
        #pragma unroll
        for (int u = 0; u < 2; ++u) {
            sa[u] = __builtin_amdgcn_mfma_f32_32x32x16_bf16(kb[es], qh[u][es],
                                                            es == 0 ? zf : sa[u], 0, 0, 0);
            sa[u] = __builtin_amdgcn_mfma_f32_32x32x16_bf16(kb[es], ql[u][es], sa[u], 0, 0, 0);
        }

    for (int kt = 0; kt < 32; ++kt) {
        // ---- V(kt) loads: coalesced, issued early, consumed by PV ----
        bf16x8 vb[2][2];
        {
            const ushort* vp = vfb + (size_t)kt * 2048;
            #pragma unroll
            for (int ks = 0; ks < 2; ++ks)
                #pragma unroll
                for (int dg = 0; dg < 2; ++dg)
                    vb[ks][dg] = *(const bf16x8*)(vp + (ks * 2 + dg) * 512);
        }

        // ---- softmax(sa of kt) -> pf[2][2], ls; sa dead afterwards ----
        // sa[u] = S^T[k][q]: lane owns col q, reg r -> k=(r&3)+8*(r>>2)+4*half
        bf16x8 pf[2][2];
        #pragma unroll
        for (int ks = 0; ks < 2; ++ks) {
            #pragma unroll
            for (int u = 0; u < 2; ++u) {
                const float p0 = fast_exp2(sa[u][8 * ks + 0]);
                const float p1 = fast_exp2(sa[u][8 * ks + 1]);
                const float p2 = fast_exp2(sa[u][8 * ks + 2]);
                const float p3 = fast_exp2(sa[u][8 * ks + 3]);
                const float p4 = fast_exp2(sa[u][8 * ks + 4]);
                const float p5 = fast_exp2(sa[u][8 * ks + 5]);
                const float p6 = fast_exp2(sa[u][8 * ks + 6]);
                const float p7 = fast_exp2(sa[u][8 * ks + 7]);
                ls[u] += ((p0 + p1) + (p2 + p3)) + ((p4 + p5) + (p6 + p7));

                // Own regs (local k within the 16-key group):
                //   half=0: a0={0,1} a1={2,3} b0={8,9}  b1={10,11}
                //   half=1: a0={4,5} a1={6,7} b0={12,13} b1={14,15}
                // Lane needs k = half*8 + 0..7 of column q=lid.
                uint a0 = pk_bf16(p0, p1);
                uint a1 = pk_bf16(p2, p3);
                uint b0 = pk_bf16(p4, p5);
                uint b1 = pk_bf16(p6, p7);
                // a[32:63] <- b[0:31]; b[0:31] <- a[32:63]:
                //   a0 -> half0:{0,1}  half1:{8,9}   = W0
                //   b0 -> half0:{4,5}  half1:{12,13} = W2
                permswap(a0, b0);
                permswap(a1, b1);            // a1 = W1, b1 = W3
                union { uint w[4]; bf16x8 v; } pu;
                pu.w[0] = a0; pu.w[1] = a1; pu.w[2] = b0; pu.w[3] = b1;
                pf[ks][u] = pu.v;
            }
        }

        // ---- advance K: kb <- kn, prefetch K(kt+2), coalesced ----
        #pragma unroll
        for (int es = 0; es < 4; ++es) kb[es] = kn[es];
        {
            const ushort* kp = kfb + (size_t)((kt + 2) & 31) * 2048;
            #pragma unroll
            for (int es = 0; es < 4; ++es) kn[es] = *(const bf16x8*)(kp + es * 512);
        }

        // ---- QK(kt+1) -> sa (zf-seeded; kt=31 computes an unused tile) ----
        __builtin_amdgcn_s_setprio(1);
        #pragma unroll
        for (int es = 0; es < 4; ++es)
            #pragma unroll
            for (int u = 0; u < 2; ++u) {
                sa[u] = __builtin_amdgcn_mfma_f32_32x32x16_bf16(kb[es], qh[u][es],
                                                                es == 0 ? zf : sa[u], 0, 0, 0);
                sa[u] = __builtin_amdgcn_mfma_f32_32x32x16_bf16(kb[es], ql[u][es], sa[u], 0, 0, 0);
            }
        __builtin_amdgcn_s_setprio(0);

        // ---- PV(kt): o += V^T(kt) x P^T(kt) ----
        __builtin_amdgcn_s_setprio(1);
        #pragma unroll
        for (int ks = 0; ks < 2; ++ks)
            #pragma unroll
            for (int dg = 0; dg < 2; ++dg)
                #pragma unroll
                for (int u = 0; u < 2; ++u)
                    o[u][dg] = __builtin_amdgcn_mfma_f32_32x32x16_bf16(vb[ks][dg], pf[ks][u], o[u][dg], 0, 0, 0);
        __builtin_amdgcn_s_setprio(0);
    }

    // ---- epilogue: combine half-lane partial sums, scale, store O^T ----
    const int b = bh >> 4, hh = bh & 15;
    #pragma unroll
    for (int u = 0; u < 2; ++u) {
        float lsv = ls[u];
        lsv += __shfl_xor(lsv, 32);
        const float sc = wl / lsv;
        const int q = qbase + u * 32 + lid;
        float* pb = part + (size_t)l * (ROWS_PL * DMODEL)
                  + ((size_t)q * BATCH + b) * DMODEL + hh * HDIM;
        #pragma unroll
        for (int dg = 0; dg < 2; ++dg)
            #pragma unroll
            for (int rq = 0; rq < 4; ++rq) {
                float4 vv;
                vv.x = o[u][dg][rq * 4 + 0] * sc;
                vv.y = o[u][dg][rq * 4 + 1] * sc;
                vv.z = o[u][dg][rq * 4 + 2] * sc;
                vv.w = o[u][dg][rq * 4 + 3] * sc;
                *(float4*)(pb + dg * 32 + rq * 8 + half * 4) = vv;
            }
    }
}

// ---------------------------------------------------------------------------
// Sum the 4 layer partials -> bf16 hi plane for the O projection.
// ---------------------------------------------------------------------------
__global__ __launch_bounds__(256)
void sum_y(const float* __restrict__ part, ushort* __restrict__ YH)
{
    const int i = (blockIdx.x * 256 + threadIdx.x) * 8;
    float acc[8];
    #pragma unroll
    for (int c = 0; c < 2; ++c) {
        float4 s = *(const float4*)(part + i + c * 4);
        #pragma unroll
        for (int l = 1; l < LP1; ++l) {
            const float4 p = *(const float4*)(part + (size_t)l * 2097152 + i + c * 4);
            s.x += p.x; s.y += p.y; s.z += p.z; s.w += p.w;
        }
        acc[c * 4 + 0] = s.x; acc[c * 4 + 1] = s.y;
        acc[c * 4 + 2] = s.z; acc[c * 4 + 3] = s.w;
    }
    uint out[4];
    #pragma unroll
    for (int c = 0; c < 4; ++c) out[c] = pk_bf16(acc[c * 2], acc[c * 2 + 1]);
    *(uint4*)(YH + i) = *(uint4*)out;
}

// ---------------------------------------------------------------------------
extern "C" void kernel_launch(void* const* d_in, const int* in_sizes, int n_in,
                              void* d_out, int out_size, void* d_ws, size_t ws_size,
                              hipStream_t stream) {
    const float* x  = (const float*)d_in[0];
    const float* lo = (const float*)d_in[1];
    const float* Wq = (const float*)d_in[2];
    const float* bq = (const float*)d_in[3];
    const float* Wk = (const float*)d_in[4];
    const float* bk = (const float*)d_in[5];
    const float* Wv = (const float*)d_in[6];
    const float* bv = (const float*)d_in[7];
    const float* Wo = (const float*)d_in[8];
    const float* bo = (const float*)d_in[9];
    const float* lw = (const float*)d_in[10];
    float* out = (float*)d_out;

    char* ws = (char*)d_ws;
    ushort* XsH  = (ushort*)(ws);                          // 16,777,216 B
    ushort* WH   = (ushort*)(ws + 16777216);               //  8,388,608 B
    ushort* WL   = (ushort*)(ws + 25165824);               //  8,388,608 B (Wq/Wo only)
    ushort* qhb  = (ushort*)(ws + 33554432);               //  4,194,304 B
    ushort* qlb  = (ushort*)(ws + 37748736);               //  4,194,304 B
    ushort* khb  = (ushort*)(ws + 41943040);               // 16,777,216 B
    ushort* vthb = (ushort*)(ws + 58720256);               // 16,777,216 B
    float*  part = (float*)(ws + 75497472);                // 33,554,432 B
    ushort* YH   = (ushort*)(ws + 109051904);              //  4,194,304 B
    // total 113,246,208 B

    dim3 blk(256);
    // Xs -> hi plane; Wq/Wo -> hi+lo; Wk/Wv -> hi only
    presplit<<<dim3(3072, 1, 6), blk, 0, stream>>>(x, lo, Wq, Wk, Wv, Wo, XsH, WH, WL);
    // Q projection (glds dbuf): pre-scaled hi/lo planes [b*16+h][s][e]
    proj_g<0><<<dim3(512), blk, 0, stream>>>(XsH, WH, WL, bq, nullptr, qhb, qlb);
    // fused K+V projection (glds dbuf, hi-only weights, fragment-linear outputs)
    proj_kv<<<dim3(8, 128), blk, 0, stream>>>(XsH,
        WH + 1048576, WH + 2097152, bk, bv, khb, vthb);
    // attention: 512 XCD-swizzled blocks -> per-layer fp32 partials
    attn_mfma<<<dim3(512), blk, 0, stream>>>(qhb, qlb, khb, vthb, lw, part);
    // reduce 4 partials -> bf16 hi plane
    sum_y<<<dim3(1024), blk, 0, stream>>>(part, YH);
    // output projection (glds dbuf)
    proj_g<1><<<dim3(512), blk, 0, stream>>>(YH, WH + 3145728, WL + 3145728, bo, out, nullptr, nullptr);
}

// Round 9
// 247.179 us; speedup vs baseline: 1.1507x; 1.0048x over previous
//
#include <hip/hip_runtime.h>
#include <hip/hip_bf16.h>
#include <math.h>

// Problem constants (fixed by reference setup)
#define S_LEN   1024
#define BATCH   2
#define DMODEL  1024
#define NHEADS  16
#define HDIM    64
#define BHEADS  32          // BATCH*NHEADS
#define LP1     4           // 1 + L layers
#define ROWS_PL 2048        // S*B rows per layer

typedef __attribute__((ext_vector_type(8)))  short bf16x8;   // 8 bf16 = 4 VGPRs
typedef __attribute__((ext_vector_type(4)))  float f32x4;
typedef __attribute__((ext_vector_type(16))) float f32x16;

__device__ inline ushort bf16_rne(float a) {
    unsigned u = __float_as_uint(a);
    return (ushort)((u + 0x7FFFu + ((u >> 16) & 1u)) >> 16);
}
__device__ inline float bf16_up(ushort h) { return __uint_as_float(((unsigned)h) << 16); }
__device__ inline void split_bf16(float a, ushort &hi, ushort &lo) {
    hi = bf16_rne(a);
    lo = bf16_rne(a - bf16_up(hi));
}
// packed f32x2 -> bf16x2 (v_cvt_pk_bf16_f32)
__device__ inline uint pk_bf16(float a, float b) {
    float2 f; f.x = a; f.y = b;
    __hip_bfloat162 h = __float22bfloat162_rn(f);
    return *reinterpret_cast<uint*>(&h);
}
// raw v_exp_f32 (no denormal fixup path)
#if __has_builtin(__builtin_amdgcn_exp2f)
__device__ inline float fast_exp2(float x) { return __builtin_amdgcn_exp2f(x); }
#else
__device__ inline float fast_exp2(float x) { return exp2f(x); }
#endif

// v_permlane32_swap_b32 a, b:  a[32:63] <- b[0:31] ; b[0:31] <- a[32:63]
// (verified on HW in rounds 2-6: passed with identical absmax)
__device__ inline void permswap(uint &a, uint &b) {
    asm("v_permlane32_swap_b32 %0, %1" : "+v"(a), "+v"(b));
}

// Async global->LDS, 16 B per lane. HW places lane i at lds_base + i*16.
__device__ inline void glds16(const ushort* g, ushort* l) {
    __builtin_amdgcn_global_load_lds(
        (const __attribute__((address_space(1))) void*)g,
        (__attribute__((address_space(3))) void*)l, 16, 0, 0);
}

// hd^-0.5 * log2(e), folded into the Q projection epilogue
#define SCLF 0.18033688011112042f

// ---------------------------------------------------------------------------
// One-shot pre-split: Xs = [x ; layer_outputs] -> hi bf16 plane;
// Wq/Wo -> hi+lo planes; Wk/Wv -> hi plane only (lo dropped: its contribution
// is below the bf16 rounding already applied to K/V outputs).
// ---------------------------------------------------------------------------
__global__ __launch_bounds__(256)
void presplit(const float* __restrict__ x, const float* __restrict__ lo,
              const float* __restrict__ Wq, const float* __restrict__ Wk,
              const float* __restrict__ Wv, const float* __restrict__ Wo,
              ushort* __restrict__ XsH, ushort* __restrict__ WH,
              ushort* __restrict__ WL)
{
    const int z = blockIdx.z;
    const float* src; ushort* dh; ushort* dl = nullptr; int n;
    if (z == 0)      { src = x;  dh = XsH;           n = 2097152; }
    else if (z == 1) { src = lo; dh = XsH + 2097152; n = 6291456; }
    else {
        const float* wsrc[4] = { Wq, Wk, Wv, Wo };
        src = wsrc[z - 2];
        dh = WH + (size_t)(z - 2) * 1048576;
        if (z == 2 || z == 5) dl = WL + (size_t)(z - 2) * 1048576;
        n = 1048576;
    }
    const int i = (blockIdx.x * 256 + threadIdx.x) * 8;
    if (i >= n) return;
    float v[8];
    *(float4*)&v[0] = *(const float4*)(src + i);
    *(float4*)&v[4] = *(const float4*)(src + i + 4);
    ushort h[8];
    #pragma unroll
    for (int j = 0; j < 8; ++j) h[j] = bf16_rne(v[j]);
    *(uint4*)(dh + i) = *(uint4*)h;
    if (dl) {
        ushort l[8];
        #pragma unroll
        for (int j = 0; j < 8; ++j) l[j] = bf16_rne(v[j] - bf16_up(h[j]));
        *(uint4*)(dl + i) = *(uint4*)l;
    }
}

// ---------------------------------------------------------------------------
// MERGED Q + KV projection, one dispatch, interleaved block IDs so CUs
// co-reside Q blocks and KV blocks (heterogeneous overlap). glds-staged,
// double-buffered (one barrier/K-step), XOR chunk swizzle.
//
// odd bid  -> Q path:  BM=BN=64, C=A_hi@(Wq_hi+Wq_lo)^T, scaled, split into
//                      hi/lo planes at [b*16+h][s][e]      (512 blocks)
// even bid -> KV path: BM=128, BN=128, hi-only weights, K and V fused.
//   K out: fragment-linear khb[bhI][kt][es][lane][8],  lane=half*32+(s&31)
//   V out: LDS transpose -> vthb[bhI][kt][ks*2+dg][lane][8], lane=half*32+(e&31)
// ---------------------------------------------------------------------------
__global__ __launch_bounds__(256, 2)
void proj_qkv(const ushort* __restrict__ XsH,
              const ushort* __restrict__ WH, const ushort* __restrict__ WL,
              const float* __restrict__ bq, const float* __restrict__ bk,
              const float* __restrict__ bv,
              ushort* __restrict__ qhb, ushort* __restrict__ qlb,
              ushort* __restrict__ kout, ushort* __restrict__ vout)
{
    __shared__ ushort smem[2][12288];    // 48 KB total; Q path uses 12 KB of it
    const int bid = blockIdx.x;
    const int t   = threadIdx.x;
    const int wv  = t >> 6, lane = t & 63;
    const int quad = lane >> 4, r = lane & 15;
    const int lrow = lane >> 2;
    const int lch  = ((lane & 3) ^ (lrow & 3)) * 8;      // XOR chunk swizzle
    const int q0x  = (quad ^ (r & 3)) << 3;              // swizzled frag chunk
    const int cn   = lane & 15;

    if (bid & 1) {
        // =============== Q path (BM=BN=64, hi+lo weights) ===============
        const int fid = bid >> 1;
        const int nt = (fid & 7) * 2 + ((fid >> 3) & 1);
        const int mt = fid >> 4;
        const int m0 = mt * 64, n0 = nt * 64;

        const int wm = wv & 1, wn = wv >> 1;
        const int mBase = wm * 32, nBase = wn * 32;

        const ushort* Asrc  = XsH + (size_t)(m0 + wv * 16 + lrow) * DMODEL + lch;
        const ushort* Bhsrc = WH  + (size_t)(n0 + wv * 16 + lrow) * DMODEL + lch;
        const ushort* Blsrc = WL  + (size_t)(n0 + wv * 16 + lrow) * DMODEL + lch;

        f32x4 acc[2][2];
        #pragma unroll
        for (int i = 0; i < 2; ++i)
            #pragma unroll
            for (int j = 0; j < 2; ++j) acc[i][j] = (f32x4){0.f, 0.f, 0.f, 0.f};

        glds16(Asrc,  smem[0]        + wv * 512);
        glds16(Bhsrc, smem[0] + 2048 + wv * 512);
        glds16(Blsrc, smem[0] + 4096 + wv * 512);

        for (int k = 0; k < 32; ++k) {
            const int cur = k & 1;
            __syncthreads();
            if (k + 1 < 32) {
                const int off = (k + 1) * 32;
                glds16(Asrc  + off, smem[cur ^ 1]        + wv * 512);
                glds16(Bhsrc + off, smem[cur ^ 1] + 2048 + wv * 512);
                glds16(Blsrc + off, smem[cur ^ 1] + 4096 + wv * 512);
            }
            const ushort* Ah = smem[cur];
            const ushort* Bh = smem[cur] + 2048;
            const ushort* Bl = smem[cur] + 4096;
            bf16x8 fa[2], fbh[2], fbl[2];
            #pragma unroll
            for (int i = 0; i < 2; ++i)
                fa[i] = *(const bf16x8*)&Ah[(mBase + i * 16 + r) * 32 + q0x];
            #pragma unroll
            for (int j = 0; j < 2; ++j) {
                fbh[j] = *(const bf16x8*)&Bh[(nBase + j * 16 + r) * 32 + q0x];
                fbl[j] = *(const bf16x8*)&Bl[(nBase + j * 16 + r) * 32 + q0x];
            }
            #pragma unroll
            for (int i = 0; i < 2; ++i)
                #pragma unroll
                for (int j = 0; j < 2; ++j) {
                    acc[i][j] = __builtin_amdgcn_mfma_f32_16x16x32_bf16(fa[i], fbh[j], acc[i][j], 0, 0, 0);
                    acc[i][j] = __builtin_amdgcn_mfma_f32_16x16x32_bf16(fa[i], fbl[j], acc[i][j], 0, 0, 0);
                }
        }

        #pragma unroll
        for (int j = 0; j < 2; ++j) {
            const int n = n0 + nBase + j * 16 + cn;
            const float bvv = bq[n];
            #pragma unroll
            for (int i = 0; i < 2; ++i) {
                const int mrow = m0 + mBase + i * 16 + quad * 4;
                #pragma unroll
                for (int g = 0; g < 4; ++g) {
                    const int m = mrow + g;
                    const float val = (acc[i][j][g] + bvv) * SCLF;  // fold attn scale
                    const int s = m >> 1, b = m & 1;
                    const int bh = b * 16 + (n >> 6), e = n & 63;
                    const size_t idx = (((size_t)bh * S_LEN) + s) * HDIM + e;
                    ushort hi, lov; split_bf16(val, hi, lov);
                    qhb[idx] = hi; qlb[idx] = lov;
                }
            }
        }
    } else {
        // =============== KV path (BM=128, BN=128, hi-only) ===============
        const int fid = bid >> 1;
        const int n0 = (fid & 7) * 128;
        const int m0 = (fid >> 3) * 128;
        const int lyr = m0 >> 11;

        const int wm = wv & 1, wn = wv >> 1;
        const int mBase = wm * 64, nBase = wn * 64;

        const ushort* KWh = WH + 1048576;
        const ushort* VWh = WH + 2097152;
        const ushort* Asrc0 = XsH + (size_t)(m0 + wv * 16 + lrow) * DMODEL + lch;
        const ushort* Asrc1 = Asrc0 + (size_t)64 * DMODEL;
        const ushort* Bw[2] = { KWh, VWh };
        const ushort* Bsrc[2][2];
        #pragma unroll
        for (int p = 0; p < 2; ++p)
            #pragma unroll
            for (int seg = 0; seg < 2; ++seg)
                Bsrc[p][seg] = Bw[p] + (size_t)(n0 + wv * 32 + seg * 16 + lrow) * DMODEL + lch;

        f32x4 aK[4][4], aV[4][4];
        #pragma unroll
        for (int i = 0; i < 4; ++i)
            #pragma unroll
            for (int j = 0; j < 4; ++j) {
                aK[i][j] = (f32x4){0.f, 0.f, 0.f, 0.f};
                aV[i][j] = (f32x4){0.f, 0.f, 0.f, 0.f};
            }

        // LDS per buffer: A[128][32] at 0, K-plane[128][32] at 4096, V at 8192
        glds16(Asrc0, smem[0]        + wv * 512);
        glds16(Asrc1, smem[0] + 2048 + wv * 512);
        #pragma unroll
        for (int p = 0; p < 2; ++p)
            #pragma unroll
            for (int seg = 0; seg < 2; ++seg)
                glds16(Bsrc[p][seg], smem[0] + 4096 + p * 4096 + (wv * 2 + seg) * 512);

        for (int k = 0; k < 32; ++k) {
            const int cur = k & 1;
            __syncthreads();
            if (k + 1 < 32) {
                const int off = (k + 1) * 32;
                glds16(Asrc0 + off, smem[cur ^ 1]        + wv * 512);
                glds16(Asrc1 + off, smem[cur ^ 1] + 2048 + wv * 512);
                #pragma unroll
                for (int p = 0; p < 2; ++p)
                    #pragma unroll
                    for (int seg = 0; seg < 2; ++seg)
                        glds16(Bsrc[p][seg] + off,
                               smem[cur ^ 1] + 4096 + p * 4096 + (wv * 2 + seg) * 512);
            }
            const ushort* Ah = smem[cur];
            const ushort* Bp = smem[cur] + 4096;

            bf16x8 fa[4];
            #pragma unroll
            for (int i = 0; i < 4; ++i)
                fa[i] = *(const bf16x8*)&Ah[(mBase + i * 16 + r) * 32 + q0x];
            #pragma unroll
            for (int j = 0; j < 4; ++j) {
                const int off2 = (nBase + j * 16 + r) * 32 + q0x;
                const bf16x8 fkh = *(const bf16x8*)&Bp[off2];
                const bf16x8 fvh = *(const bf16x8*)&Bp[4096 + off2];
                #pragma unroll
                for (int i = 0; i < 4; ++i) {
                    aK[i][j] = __builtin_amdgcn_mfma_f32_16x16x32_bf16(fa[i], fkh, aK[i][j], 0, 0, 0);
                    aV[i][j] = __builtin_amdgcn_mfma_f32_16x16x32_bf16(fa[i], fvh, aV[i][j], 0, 0, 0);
                }
            }
        }

        // ---- K epilogue: fragment-linear [bhI][kt][es][lane][8] ----
        #pragma unroll
        for (int j = 0; j < 4; ++j) {
            const int n = n0 + nBase + j * 16 + cn;
            const float bb = bk[n];
            const int e    = n & 63;
            const int es_k = e >> 4, half_k = (e >> 3) & 1, j_k = e & 7;
            const int h    = n >> 6;
            #pragma unroll
            for (int i = 0; i < 4; ++i) {
                #pragma unroll
                for (int g = 0; g < 4; ++g) {
                    const int m = m0 + mBase + i * 16 + quad * 4 + g;
                    const int rem = m & 2047, s = rem >> 1, b = rem & 1;
                    const int bhI = lyr * 32 + b * 16 + h;
                    const int kt  = s >> 5;
                    const int lnk = half_k * 32 + (s & 31);
                    kout[(size_t)bhI * 65536 + (size_t)(kt * 4 + es_k) * 512 + lnk * 8 + j_k]
                        = bf16_rne(aK[i][j][g] + bb);
                }
            }
        }

        // ---- V epilogue: transpose via LDS [128][130], fragment-linear ----
        ushort* T = &smem[0][0];   // 128*130 = 16,640 ushorts <= 24,576 total
        __syncthreads();
        #pragma unroll
        for (int j = 0; j < 4; ++j) {
            const int nloc = nBase + j * 16 + cn;
            const float bb = bv[n0 + nloc];
            #pragma unroll
            for (int i = 0; i < 4; ++i) {
                #pragma unroll
                for (int g = 0; g < 4; ++g) {
                    const int mloc = mBase + i * 16 + quad * 4 + g;
                    T[nloc * 130 + mloc] = bf16_rne(aV[i][j][g] + bb);
                }
            }
        }
        __syncthreads();
        {
            const int nloc = t >> 1, bsel = t & 1;
            const int n = n0 + nloc, h = n >> 6;
            const int e = n & 63;
            const int dg = e >> 5, lid_v = e & 31;
            const int s0g = (m0 & 2047) >> 1;      // multiple of 64
            const int kt0 = s0g >> 5;
            const int bhI = lyr * 32 + bsel * 16 + h;
            #pragma unroll
            for (int c = 0; c < 8; ++c) {
                ushort tmp[8];
                #pragma unroll
                for (int j = 0; j < 8; ++j)
                    tmp[j] = T[nloc * 130 + 2 * (c * 8 + j) + bsel];
                const int kt = kt0 + (c >> 2);
                const int c2 = c & 3;
                const int ks = c2 >> 1, hv = c2 & 1;
                ushort* dstb = vout + (size_t)bhI * 65536 + (size_t)kt * 2048;
                *(uint4*)(dstb + (ks * 2 + dg) * 512 + (hv * 32 + lid_v) * 8) = *(uint4*)tmp;
            }
        }
    }
}

// ---------------------------------------------------------------------------
// O projection, glds staging, double-buffered. BM=BN=64, BK=32, 256 thr.
// fp32 row-major out[m][n].
// ---------------------------------------------------------------------------
__global__ __launch_bounds__(256)
void proj_o(const ushort* __restrict__ Abf,
            const ushort* __restrict__ Bhg, const ushort* __restrict__ Blg,
            const float* __restrict__ bias, float* __restrict__ outf)
{
    __shared__ ushort smem[2][3 * 2048];   // dbuf x {Ah, Bh, Bl}: 24 KB

    const int fid = blockIdx.x;
    const int nt = (fid & 7) * 2 + ((fid >> 3) & 1);
    const int mt = fid >> 4;
    const int m0 = mt * 64, n0 = nt * 64;

    const int t  = threadIdx.x;
    const int wv = t >> 6, lane = t & 63;
    const int quad = lane >> 4, r = lane & 15;
    const int wm = wv & 1, wn = wv >> 1;
    const int mBase = wm * 32, nBase = wn * 32;

    const int lrow = lane >> 2;
    const int lch  = ((lane & 3) ^ (lrow & 3)) * 8;      // XOR chunk swizzle
    const ushort* Asrc  = Abf + (size_t)(m0 + wv * 16 + lrow) * DMODEL + lch;
    const ushort* Bhsrc = Bhg + (size_t)(n0 + wv * 16 + lrow) * DMODEL + lch;
    const ushort* Blsrc = Blg + (size_t)(n0 + wv * 16 + lrow) * DMODEL + lch;

    const int q0x = (quad ^ (r & 3)) << 3;
    f32x4 acc[2][2];
    #pragma unroll
    for (int i = 0; i < 2; ++i)
        #pragma unroll
        for (int j = 0; j < 2; ++j) acc[i][j] = (f32x4){0.f, 0.f, 0.f, 0.f};

    glds16(Asrc,  smem[0]        + wv * 512);
    glds16(Bhsrc, smem[0] + 2048 + wv * 512);
    glds16(Blsrc, smem[0] + 4096 + wv * 512);

    for (int k = 0; k < 32; ++k) {
        const int cur = k & 1;
        __syncthreads();
        if (k + 1 < 32) {
            const int off = (k + 1) * 32;
            glds16(Asrc  + off, smem[cur ^ 1]        + wv * 512);
            glds16(Bhsrc + off, smem[cur ^ 1] + 2048 + wv * 512);
            glds16(Blsrc + off, smem[cur ^ 1] + 4096 + wv * 512);
        }
        const ushort* Ah = smem[cur];
        const ushort* Bh = smem[cur] + 2048;
        const ushort* Bl = smem[cur] + 4096;
        bf16x8 fa[2], fbh[2], fbl[2];
        #pragma unroll
        for (int i = 0; i < 2; ++i)
            fa[i] = *(const bf16x8*)&Ah[(mBase + i * 16 + r) * 32 + q0x];
        #pragma unroll
        for (int j = 0; j < 2; ++j) {
            fbh[j] = *(const bf16x8*)&Bh[(nBase + j * 16 + r) * 32 + q0x];
            fbl[j] = *(const bf16x8*)&Bl[(nBase + j * 16 + r) * 32 + q0x];
        }
        #pragma unroll
        for (int i = 0; i < 2; ++i)
            #pragma unroll
            for (int j = 0; j < 2; ++j) {
                acc[i][j] = __builtin_amdgcn_mfma_f32_16x16x32_bf16(fa[i], fbh[j], acc[i][j], 0, 0, 0);
                acc[i][j] = __builtin_amdgcn_mfma_f32_16x16x32_bf16(fa[i], fbl[j], acc[i][j], 0, 0, 0);
            }
    }

    const int cn = lane & 15;
    #pragma unroll
    for (int j = 0; j < 2; ++j) {
        const int n = n0 + nBase + j * 16 + cn;
        const float bvv = bias[n];
        #pragma unroll
        for (int i = 0; i < 2; ++i) {
            const int mrow = m0 + mBase + i * 16 + quad * 4;
            #pragma unroll
            for (int g = 0; g < 4; ++g)
                outf[(size_t)(mrow + g) * DMODEL + n] = acc[i][j][g] + bvv;
        }
    }
}

// ---------------------------------------------------------------------------
// MFMA flash attention, swapped-operand layout (zero LDS, zero barriers),
// u=2 query tiles per wave (64 q), software-pipelined, FRAGMENT-LINEAR K/V
// (coalesced base+lane*16B loads). QK chains seeded with a persistent zero
// C-vector. Grid 512, XCD-swizzled.
// ---------------------------------------------------------------------------
__global__ __launch_bounds__(256, 2)
void attn_mfma(const ushort* __restrict__ qhg, const ushort* __restrict__ qlg,
               const ushort* __restrict__ kh, const ushort* __restrict__ vth,
               const float* __restrict__ lwraw, float* __restrict__ part)
{
    const int t    = threadIdx.x;
    const int wv   = t >> 6, lane = t & 63;
    const int half = lane >> 5, lid = lane & 31;

    const int fid  = blockIdx.x;                 // 512 blocks
    const int xcd  = fid & 7, slot = fid >> 3;   // slot in [0,64)
    const int pair = xcd * 16 + (slot >> 2);     // 16 (bh,l) pairs per XCD
    const int qt   = slot & 3;                   // 4 q-tiles of 256 per pair
    const int bh   = pair & 31, l = pair >> 5;
    const int qbase = qt * 256 + wv * 64;        // wave owns 64 queries

    float wl;
    {
        float v[LP1], wm = -3.0e38f;
        #pragma unroll
        for (int i = 0; i < LP1; ++i) { v[i] = lwraw[i]; wm = fmaxf(wm, v[i]); }
        float ws = 0.f;
        #pragma unroll
        for (int i = 0; i < LP1; ++i) { v[i] = __expf(v[i] - wm); ws += v[i]; }
        wl = v[l] / ws;
    }

    // Q fragments (B-frag: lane owns query row qbase+u*32+lid, 8 dims/frag)
    bf16x8 qh[2][4], ql[2][4];
    #pragma unroll
    for (int u = 0; u < 2; ++u) {
        const size_t qoff = ((size_t)bh * S_LEN + qbase + u * 32 + lid) * HDIM + half * 8;
        #pragma unroll
        for (int es = 0; es < 4; ++es) {
            qh[u][es] = *(const bf16x8*)(qhg + qoff + es * 16);
            ql[u][es] = *(const bf16x8*)(qlg + qoff + es * 16);
        }
    }

    f32x16 o[2][2];
    #pragma unroll
    for (int u = 0; u < 2; ++u)
        #pragma unroll
        for (int dg = 0; dg < 2; ++dg)
            #pragma unroll
            for (int i = 0; i < 16; ++i) o[u][dg][i] = 0.f;
    float ls[2] = {0.f, 0.f};

    // persistent zero C-operand: seeds each QK chain, never re-written
    f32x16 zf;
    #pragma unroll
    for (int i = 0; i < 16; ++i) zf[i] = 0.f;

    // fragment-linear bases: every load below is base + lane*16B (coalesced)
    const size_t kvo = (size_t)(l * BHEADS + bh) * S_LEN * HDIM;
    const ushort* kfb = kh  + kvo + (size_t)lane * 8;
    const ushort* vfb = vth + kvo + (size_t)lane * 8;

    // ---- prologue: K(0) -> kb; sa = QK(K(0)); K(1) -> kn ----
    bf16x8 kb[4], kn[4];
    #pragma unroll
    for (int es = 0; es < 4; ++es)
        kb[es] = *(const bf16x8*)(kfb + es * 512);
    #pragma unroll
    for (int es = 0; es < 4; ++es)
        kn[es] = *(const bf16x8*)(kfb + 2048 + es * 512);

    f32x16 sa[2];
    #pragma unroll
    for (int es = 0; es < 4; ++es)
        #pragma unroll
        for (int u = 0; u < 2; ++u) {
            sa[u] = __builtin_amdgcn_mfma_f32_32x32x16_bf16(kb[es], qh[u][es],
                                                            es == 0 ? zf : sa[u], 0, 0, 0);
            sa[u] = __builtin_amdgcn_mfma_f32_32x32x16_bf16(kb[es], ql[u][es], sa[u], 0, 0, 0);
        }

    for (int kt = 0; kt < 32; ++kt) {
        // ---- V(kt) loads: coalesced, issued early, consumed by PV ----
        bf16x8 vb[2][2];
        {
            const ushort* vp = vfb + (size_t)kt * 2048;
            #pragma unroll
            for (int ks = 0; ks < 2; ++ks)
                #pragma unroll
                for (int dg = 0; dg < 2; ++dg)
                    vb[ks][dg] = *(const bf16x8*)(vp + (ks * 2 + dg) * 512);
        }

        // ---- softmax(sa of kt) -> pf[2][2], ls; sa dead afterwards ----
        // sa[u] = S^T[k][q]: lane owns col q, reg r -> k=(r&3)+8*(r>>2)+4*half
        bf16x8 pf[2][2];
        #pragma unroll
        for (int ks = 0; ks < 2; ++ks) {
            #pragma unroll
            for (int u = 0; u < 2; ++u) {
                const float p0 = fast_exp2(sa[u][8 * ks + 0]);
                const float p1 = fast_exp2(sa[u][8 * ks + 1]);
                const float p2 = fast_exp2(sa[u][8 * ks + 2]);
                const float p3 = fast_exp2(sa[u][8 * ks + 3]);
                const float p4 = fast_exp2(sa[u][8 * ks + 4]);
                const float p5 = fast_exp2(sa[u][8 * ks + 5]);
                const float p6 = fast_exp2(sa[u][8 * ks + 6]);
                const float p7 = fast_exp2(sa[u][8 * ks + 7]);
                ls[u] += ((p0 + p1) + (p2 + p3)) + ((p4 + p5) + (p6 + p7));

                // Own regs (local k within the 16-key group):
                //   half=0: a0={0,1} a1={2,3} b0={8,9}  b1={10,11}
                //   half=1: a0={4,5} a1={6,7} b0={12,13} b1={14,15}
                // Lane needs k = half*8 + 0..7 of column q=lid.
                uint a0 = pk_bf16(p0, p1);
                uint a1 = pk_bf16(p2, p3);
                uint b0 = pk_bf16(p4, p5);
                uint b1 = pk_bf16(p6, p7);
                // a[32:63] <- b[0:31]; b[0:31] <- a[32:63]:
                //   a0 -> half0:{0,1}  half1:{8,9}   = W0
                //   b0 -> half0:{4,5}  half1:{12,13} = W2
                permswap(a0, b0);
                permswap(a1, b1);            // a1 = W1, b1 = W3
                union { uint w[4]; bf16x8 v; } pu;
                pu.w[0] = a0; pu.w[1] = a1; pu.w[2] = b0; pu.w[3] = b1;
                pf[ks][u] = pu.v;
            }
        }

        // ---- advance K: kb <- kn, prefetch K(kt+2), coalesced ----
        #pragma unroll
        for (int es = 0; es < 4; ++es) kb[es] = kn[es];
        {
            const ushort* kp = kfb + (size_t)((kt + 2) & 31) * 2048;
            #pragma unroll
            for (int es = 0; es < 4; ++es) kn[es] = *(const bf16x8*)(kp + es * 512);
        }

        // ---- QK(kt+1) -> sa (zf-seeded; kt=31 computes an unused tile) ----
        __builtin_amdgcn_s_setprio(1);
        #pragma unroll
        for (int es = 0; es < 4; ++es)
            #pragma unroll
            for (int u = 0; u < 2; ++u) {
                sa[u] = __builtin_amdgcn_mfma_f32_32x32x16_bf16(kb[es], qh[u][es],
                                                                es == 0 ? zf : sa[u], 0, 0, 0);
                sa[u] = __builtin_amdgcn_mfma_f32_32x32x16_bf16(kb[es], ql[u][es], sa[u], 0, 0, 0);
            }
        __builtin_amdgcn_s_setprio(0);

        // ---- PV(kt): o += V^T(kt) x P^T(kt) ----
        __builtin_amdgcn_s_setprio(1);
        #pragma unroll
        for (int ks = 0; ks < 2; ++ks)
            #pragma unroll
            for (int dg = 0; dg < 2; ++dg)
                #pragma unroll
                for (int u = 0; u < 2; ++u)
                    o[u][dg] = __builtin_amdgcn_mfma_f32_32x32x16_bf16(vb[ks][dg], pf[ks][u], o[u][dg], 0, 0, 0);
        __builtin_amdgcn_s_setprio(0);
    }

    // ---- epilogue: combine half-lane partial sums, scale, store O^T ----
    const int b = bh >> 4, hh = bh & 15;
    #pragma unroll
    for (int u = 0; u < 2; ++u) {
        float lsv = ls[u];
        lsv += __shfl_xor(lsv, 32);
        const float sc = wl / lsv;
        const int q = qbase + u * 32 + lid;
        float* pb = part + (size_t)l * (ROWS_PL * DMODEL)
                  + ((size_t)q * BATCH + b) * DMODEL + hh * HDIM;
        #pragma unroll
        for (int dg = 0; dg < 2; ++dg)
            #pragma unroll
            for (int rq = 0; rq < 4; ++rq) {
                float4 vv;
                vv.x = o[u][dg][rq * 4 + 0] * sc;
                vv.y = o[u][dg][rq * 4 + 1] * sc;
                vv.z = o[u][dg][rq * 4 + 2] * sc;
                vv.w = o[u][dg][rq * 4 + 3] * sc;
                *(float4*)(pb + dg * 32 + rq * 8 + half * 4) = vv;
            }
    }
}

// ---------------------------------------------------------------------------
// Sum the 4 layer partials -> bf16 hi plane for the O projection.
// ---------------------------------------------------------------------------
__global__ __launch_bounds__(256)
void sum_y(const float* __restrict__ part, ushort* __restrict__ YH)
{
    const int i = (blockIdx.x * 256 + threadIdx.x) * 8;
    float acc[8];
    #pragma unroll
    for (int c = 0; c < 2; ++c) {
        float4 s = *(const float4*)(part + i + c * 4);
        #pragma unroll
        for (int l = 1; l < LP1; ++l) {
            const float4 p = *(const float4*)(part + (size_t)l * 2097152 + i + c * 4);
            s.x += p.x; s.y += p.y; s.z += p.z; s.w += p.w;
        }
        acc[c * 4 + 0] = s.x; acc[c * 4 + 1] = s.y;
        acc[c * 4 + 2] = s.z; acc[c * 4 + 3] = s.w;
    }
    uint out[4];
    #pragma unroll
    for (int c = 0; c < 4; ++c) out[c] = pk_bf16(acc[c * 2], acc[c * 2 + 1]);
    *(uint4*)(YH + i) = *(uint4*)out;
}

// ---------------------------------------------------------------------------
extern "C" void kernel_launch(void* const* d_in, const int* in_sizes, int n_in,
                              void* d_out, int out_size, void* d_ws, size_t ws_size,
                              hipStream_t stream) {
    const float* x  = (const float*)d_in[0];
    const float* lo = (const float*)d_in[1];
    const float* Wq = (const float*)d_in[2];
    const float* bq = (const float*)d_in[3];
    const float* Wk = (const float*)d_in[4];
    const float* bk = (const float*)d_in[5];
    const float* Wv = (const float*)d_in[6];
    const float* bv = (const float*)d_in[7];
    const float* Wo = (const float*)d_in[8];
    const float* bo = (const float*)d_in[9];
    const float* lw = (const float*)d_in[10];
    float* out = (float*)d_out;

    char* ws = (char*)d_ws;
    ushort* XsH  = (ushort*)(ws);                          // 16,777,216 B
    ushort* WH   = (ushort*)(ws + 16777216);               //  8,388,608 B
    ushort* WL   = (ushort*)(ws + 25165824);               //  8,388,608 B (Wq/Wo only)
    ushort* qhb  = (ushort*)(ws + 33554432);               //  4,194,304 B
    ushort* qlb  = (ushort*)(ws + 37748736);               //  4,194,304 B
    ushort* khb  = (ushort*)(ws + 41943040);               // 16,777,216 B
    ushort* vthb = (ushort*)(ws + 58720256);               // 16,777,216 B
    float*  part = (float*)(ws + 75497472);                // 33,554,432 B
    ushort* YH   = (ushort*)(ws + 109051904);              //  4,194,304 B
    // total 113,246,208 B

    dim3 blk(256);
    // Xs -> hi plane; Wq/Wo -> hi+lo; Wk/Wv -> hi only
    presplit<<<dim3(3072, 1, 6), blk, 0, stream>>>(x, lo, Wq, Wk, Wv, Wo, XsH, WH, WL);
    // merged Q + KV projections (interleaved: odd bid = Q, even bid = KV)
    proj_qkv<<<dim3(1024), blk, 0, stream>>>(XsH, WH, WL, bq, bk, bv,
                                             qhb, qlb, khb, vthb);
    // attention: 512 XCD-swizzled blocks -> per-layer fp32 partials
    attn_mfma<<<dim3(512), blk, 0, stream>>>(qhb, qlb, khb, vthb, lw, part);
    // reduce 4 partials -> bf16 hi plane
    sum_y<<<dim3(1024), blk, 0, stream>>>(part, YH);
    // output projection (glds dbuf)
    proj_o<<<dim3(512), blk, 0, stream>>>(YH, WH + 3145728, WL + 3145728, bo, out);
}

// Round 10
// 234.851 us; speedup vs baseline: 1.2111x; 1.0525x over previous
//
#include <hip/hip_runtime.h>
#include <hip/hip_bf16.h>
#include <math.h>

// Problem constants (fixed by reference setup)
#define S_LEN   1024
#define BATCH   2
#define DMODEL  1024
#define NHEADS  16
#define HDIM    64
#define BHEADS  32          // BATCH*NHEADS
#define LP1     4           // 1 + L layers
#define ROWS_PL 2048        // S*B rows per layer

typedef __attribute__((ext_vector_type(8)))  short bf16x8;   // 8 bf16 = 4 VGPRs
typedef __attribute__((ext_vector_type(4)))  float f32x4;
typedef __attribute__((ext_vector_type(16))) float f32x16;

__device__ inline ushort bf16_rne(float a) {
    unsigned u = __float_as_uint(a);
    return (ushort)((u + 0x7FFFu + ((u >> 16) & 1u)) >> 16);
}
__device__ inline float bf16_up(ushort h) { return __uint_as_float(((unsigned)h) << 16); }
__device__ inline void split_bf16(float a, ushort &hi, ushort &lo) {
    hi = bf16_rne(a);
    lo = bf16_rne(a - bf16_up(hi));
}
// packed f32x2 -> bf16x2 (v_cvt_pk_bf16_f32)
__device__ inline uint pk_bf16(float a, float b) {
    float2 f; f.x = a; f.y = b;
    __hip_bfloat162 h = __float22bfloat162_rn(f);
    return *reinterpret_cast<uint*>(&h);
}
// raw v_exp_f32 (no denormal fixup path)
#if __has_builtin(__builtin_amdgcn_exp2f)
__device__ inline float fast_exp2(float x) { return __builtin_amdgcn_exp2f(x); }
#else
__device__ inline float fast_exp2(float x) { return exp2f(x); }
#endif

// v_permlane32_swap_b32 a, b:  a[32:63] <- b[0:31] ; b[0:31] <- a[32:63]
// (verified on HW in rounds 2-9: passed with identical absmax)
__device__ inline void permswap(uint &a, uint &b) {
    asm("v_permlane32_swap_b32 %0, %1" : "+v"(a), "+v"(b));
}

// Async global->LDS, 16 B per lane. HW places lane i at lds_base + i*16.
__device__ inline void glds16(const ushort* g, ushort* l) {
    __builtin_amdgcn_global_load_lds(
        (const __attribute__((address_space(1))) void*)g,
        (__attribute__((address_space(3))) void*)l, 16, 0, 0);
}

// hd^-0.5 * log2(e), folded into the Q projection epilogue
#define SCLF 0.18033688011112042f

// ---------------------------------------------------------------------------
// One-shot pre-split: Xs = [x ; layer_outputs] -> hi bf16 plane;
// Wq/Wo -> hi+lo planes; Wk/Wv -> hi plane only (lo dropped: its contribution
// is below the bf16 rounding already applied to K/V outputs).
// ---------------------------------------------------------------------------
__global__ __launch_bounds__(256)
void presplit(const float* __restrict__ x, const float* __restrict__ lo,
              const float* __restrict__ Wq, const float* __restrict__ Wk,
              const float* __restrict__ Wv, const float* __restrict__ Wo,
              ushort* __restrict__ XsH, ushort* __restrict__ WH,
              ushort* __restrict__ WL)
{
    const int z = blockIdx.z;
    const float* src; ushort* dh; ushort* dl = nullptr; int n;
    if (z == 0)      { src = x;  dh = XsH;           n = 2097152; }
    else if (z == 1) { src = lo; dh = XsH + 2097152; n = 6291456; }
    else {
        const float* wsrc[4] = { Wq, Wk, Wv, Wo };
        src = wsrc[z - 2];
        dh = WH + (size_t)(z - 2) * 1048576;
        if (z == 2 || z == 5) dl = WL + (size_t)(z - 2) * 1048576;
        n = 1048576;
    }
    const int i = (blockIdx.x * 256 + threadIdx.x) * 8;
    if (i >= n) return;
    float v[8];
    *(float4*)&v[0] = *(const float4*)(src + i);
    *(float4*)&v[4] = *(const float4*)(src + i + 4);
    ushort h[8];
    #pragma unroll
    for (int j = 0; j < 8; ++j) h[j] = bf16_rne(v[j]);
    *(uint4*)(dh + i) = *(uint4*)h;
    if (dl) {
        ushort l[8];
        #pragma unroll
        for (int j = 0; j < 8; ++j) l[j] = bf16_rne(v[j] - bf16_up(h[j]));
        *(uint4*)(dl + i) = *(uint4*)l;
    }
}

// ---------------------------------------------------------------------------
// MERGED Q + KV projection, one dispatch. LPT ordering: KV blocks (4x the
// work of Q blocks) at bid 0..511 so they start first; short Q blocks
// (bid 512..1023) fill the tail. glds-staged, double-buffered (one
// barrier/K-step), FULL XOR chunk swizzle: slot = chunk ^ (row&3) ^
// ((row>>2)&3) -> ds_read_b128 fragment reads are <=2-way (bank-conflict
// free); the old (row&3)-only swizzle left a 4-way conflict (4.85M
// SQ_LDS_BANK_CONFLICT measured in round 9).
//
// bid <  512 -> KV path: BM=128, BN=128, hi-only weights, K and V fused.
//   K out: fragment-linear khb[bhI][kt][es][lane][8],  lane=half*32+(s&31)
//   V out: LDS transpose -> vthb[bhI][kt][ks*2+dg][lane][8], lane=half*32+(e&31)
// bid >= 512 -> Q path:  BM=BN=64, C=A_hi@(Wq_hi+Wq_lo)^T, scaled, split
//   into hi/lo planes at [b*16+h][s][e]
// ---------------------------------------------------------------------------
__global__ __launch_bounds__(256, 2)
void proj_qkv(const ushort* __restrict__ XsH,
              const ushort* __restrict__ WH, const ushort* __restrict__ WL,
              const float* __restrict__ bq, const float* __restrict__ bk,
              const float* __restrict__ bv,
              ushort* __restrict__ qhb, ushort* __restrict__ qlb,
              ushort* __restrict__ kout, ushort* __restrict__ vout)
{
    __shared__ ushort smem[2][12288];    // 48 KB total; Q path uses 12 KB of it
    const int bid = blockIdx.x;
    const int t   = threadIdx.x;
    const int wv  = t >> 6, lane = t & 63;
    const int quad = lane >> 4, r = lane & 15;
    const int lrow = lane >> 2;
    // full XOR chunk swizzle: staging source chunk for slot (lane&3) of
    // LDS row lrow; read chunk slot for global chunk `quad` of row (..+r)
    const int lch  = ((lane & 3) ^ (lrow & 3) ^ ((lrow >> 2) & 3)) * 8;
    const int q0x  = ((quad ^ (r & 3) ^ ((r >> 2) & 3)) << 3);
    const int cn   = lane & 15;

    if (bid >= 512) {
        // =============== Q path (BM=BN=64, hi+lo weights) ===============
        const int fid = bid - 512;
        const int nt = (fid & 7) * 2 + ((fid >> 3) & 1);
        const int mt = fid >> 4;
        const int m0 = mt * 64, n0 = nt * 64;

        const int wm = wv & 1, wn = wv >> 1;
        const int mBase = wm * 32, nBase = wn * 32;

        const ushort* Asrc  = XsH + (size_t)(m0 + wv * 16 + lrow) * DMODEL + lch;
        const ushort* Bhsrc = WH  + (size_t)(n0 + wv * 16 + lrow) * DMODEL + lch;
        const ushort* Blsrc = WL  + (size_t)(n0 + wv * 16 + lrow) * DMODEL + lch;

        f32x4 acc[2][2];
        #pragma unroll
        for (int i = 0; i < 2; ++i)
            #pragma unroll
            for (int j = 0; j < 2; ++j) acc[i][j] = (f32x4){0.f, 0.f, 0.f, 0.f};

        glds16(Asrc,  smem[0]        + wv * 512);
        glds16(Bhsrc, smem[0] + 2048 + wv * 512);
        glds16(Blsrc, smem[0] + 4096 + wv * 512);

        for (int k = 0; k < 32; ++k) {
            const int cur = k & 1;
            __syncthreads();
            if (k + 1 < 32) {
                const int off = (k + 1) * 32;
                glds16(Asrc  + off, smem[cur ^ 1]        + wv * 512);
                glds16(Bhsrc + off, smem[cur ^ 1] + 2048 + wv * 512);
                glds16(Blsrc + off, smem[cur ^ 1] + 4096 + wv * 512);
            }
            const ushort* Ah = smem[cur];
            const ushort* Bh = smem[cur] + 2048;
            const ushort* Bl = smem[cur] + 4096;
            bf16x8 fa[2], fbh[2], fbl[2];
            #pragma unroll
            for (int i = 0; i < 2; ++i)
                fa[i] = *(const bf16x8*)&Ah[(mBase + i * 16 + r) * 32 + q0x];
            #pragma unroll
            for (int j = 0; j < 2; ++j) {
                fbh[j] = *(const bf16x8*)&Bh[(nBase + j * 16 + r) * 32 + q0x];
                fbl[j] = *(const bf16x8*)&Bl[(nBase + j * 16 + r) * 32 + q0x];
            }
            #pragma unroll
            for (int i = 0; i < 2; ++i)
                #pragma unroll
                for (int j = 0; j < 2; ++j) {
                    acc[i][j] = __builtin_amdgcn_mfma_f32_16x16x32_bf16(fa[i], fbh[j], acc[i][j], 0, 0, 0);
                    acc[i][j] = __builtin_amdgcn_mfma_f32_16x16x32_bf16(fa[i], fbl[j], acc[i][j], 0, 0, 0);
                }
        }

        #pragma unroll
        for (int j = 0; j < 2; ++j) {
            const int n = n0 + nBase + j * 16 + cn;
            const float bvv = bq[n];
            #pragma unroll
            for (int i = 0; i < 2; ++i) {
                const int mrow = m0 + mBase + i * 16 + quad * 4;
                #pragma unroll
                for (int g = 0; g < 4; ++g) {
                    const int m = mrow + g;
                    const float val = (acc[i][j][g] + bvv) * SCLF;  // fold attn scale
                    const int s = m >> 1, b = m & 1;
                    const int bh = b * 16 + (n >> 6), e = n & 63;
                    const size_t idx = (((size_t)bh * S_LEN) + s) * HDIM + e;
                    ushort hi, lov; split_bf16(val, hi, lov);
                    qhb[idx] = hi; qlb[idx] = lov;
                }
            }
        }
    } else {
        // =============== KV path (BM=128, BN=128, hi-only) ===============
        const int fid = bid;
        const int n0 = (fid & 7) * 128;
        const int m0 = (fid >> 3) * 128;
        const int lyr = m0 >> 11;

        const int wm = wv & 1, wn = wv >> 1;
        const int mBase = wm * 64, nBase = wn * 64;

        const ushort* KWh = WH + 1048576;
        const ushort* VWh = WH + 2097152;
        const ushort* Asrc0 = XsH + (size_t)(m0 + wv * 16 + lrow) * DMODEL + lch;
        const ushort* Asrc1 = Asrc0 + (size_t)64 * DMODEL;
        const ushort* Bw[2] = { KWh, VWh };
        const ushort* Bsrc[2][2];
        #pragma unroll
        for (int p = 0; p < 2; ++p)
            #pragma unroll
            for (int seg = 0; seg < 2; ++seg)
                Bsrc[p][seg] = Bw[p] + (size_t)(n0 + wv * 32 + seg * 16 + lrow) * DMODEL + lch;

        f32x4 aK[4][4], aV[4][4];
        #pragma unroll
        for (int i = 0; i < 4; ++i)
            #pragma unroll
            for (int j = 0; j < 4; ++j) {
                aK[i][j] = (f32x4){0.f, 0.f, 0.f, 0.f};
                aV[i][j] = (f32x4){0.f, 0.f, 0.f, 0.f};
            }

        // LDS per buffer: A[128][32] at 0, K-plane[128][32] at 4096, V at 8192
        glds16(Asrc0, smem[0]        + wv * 512);
        glds16(Asrc1, smem[0] + 2048 + wv * 512);
        #pragma unroll
        for (int p = 0; p < 2; ++p)
            #pragma unroll
            for (int seg = 0; seg < 2; ++seg)
                glds16(Bsrc[p][seg], smem[0] + 4096 + p * 4096 + (wv * 2 + seg) * 512);

        for (int k = 0; k < 32; ++k) {
            const int cur = k & 1;
            __syncthreads();
            if (k + 1 < 32) {
                const int off = (k + 1) * 32;
                glds16(Asrc0 + off, smem[cur ^ 1]        + wv * 512);
                glds16(Asrc1 + off, smem[cur ^ 1] + 2048 + wv * 512);
                #pragma unroll
                for (int p = 0; p < 2; ++p)
                    #pragma unroll
                    for (int seg = 0; seg < 2; ++seg)
                        glds16(Bsrc[p][seg] + off,
                               smem[cur ^ 1] + 4096 + p * 4096 + (wv * 2 + seg) * 512);
            }
            const ushort* Ah = smem[cur];
            const ushort* Bp = smem[cur] + 4096;

            bf16x8 fa[4];
            #pragma unroll
            for (int i = 0; i < 4; ++i)
                fa[i] = *(const bf16x8*)&Ah[(mBase + i * 16 + r) * 32 + q0x];
            #pragma unroll
            for (int j = 0; j < 4; ++j) {
                const int off2 = (nBase + j * 16 + r) * 32 + q0x;
                const bf16x8 fkh = *(const bf16x8*)&Bp[off2];
                const bf16x8 fvh = *(const bf16x8*)&Bp[4096 + off2];
                #pragma unroll
                for (int i = 0; i < 4; ++i) {
                    aK[i][j] = __builtin_amdgcn_mfma_f32_16x16x32_bf16(fa[i], fkh, aK[i][j], 0, 0, 0);
                    aV[i][j] = __builtin_amdgcn_mfma_f32_16x16x32_bf16(fa[i], fvh, aV[i][j], 0, 0, 0);
                }
            }
        }

        // ---- K epilogue: fragment-linear [bhI][kt][es][lane][8] ----
        #pragma unroll
        for (int j = 0; j < 4; ++j) {
            const int n = n0 + nBase + j * 16 + cn;
            const float bb = bk[n];
            const int e    = n & 63;
            const int es_k = e >> 4, half_k = (e >> 3) & 1, j_k = e & 7;
            const int h    = n >> 6;
            #pragma unroll
            for (int i = 0; i < 4; ++i) {
                #pragma unroll
                for (int g = 0; g < 4; ++g) {
                    const int m = m0 + mBase + i * 16 + quad * 4 + g;
                    const int rem = m & 2047, s = rem >> 1, b = rem & 1;
                    const int bhI = lyr * 32 + b * 16 + h;
                    const int kt  = s >> 5;
                    const int lnk = half_k * 32 + (s & 31);
                    kout[(size_t)bhI * 65536 + (size_t)(kt * 4 + es_k) * 512 + lnk * 8 + j_k]
                        = bf16_rne(aK[i][j][g] + bb);
                }
            }
        }

        // ---- V epilogue: transpose via LDS [128][130], fragment-linear ----
        ushort* T = &smem[0][0];   // 128*130 = 16,640 ushorts <= 24,576 total
        __syncthreads();
        #pragma unroll
        for (int j = 0; j < 4; ++j) {
            const int nloc = nBase + j * 16 + cn;
            const float bb = bv[n0 + nloc];
            #pragma unroll
            for (int i = 0; i < 4; ++i) {
                #pragma unroll
                for (int g = 0; g < 4; ++g) {
                    const int mloc = mBase + i * 16 + quad * 4 + g;
                    T[nloc * 130 + mloc] = bf16_rne(aV[i][j][g] + bb);
                }
            }
        }
        __syncthreads();
        {
            const int nloc = t >> 1, bsel = t & 1;
            const int n = n0 + nloc, h = n >> 6;
            const int e = n & 63;
            const int dg = e >> 5, lid_v = e & 31;
            const int s0g = (m0 & 2047) >> 1;      // multiple of 64
            const int kt0 = s0g >> 5;
            const int bhI = lyr * 32 + bsel * 16 + h;
            #pragma unroll
            for (int c = 0; c < 8; ++c) {
                ushort tmp[8];
                #pragma unroll
                for (int j = 0; j < 8; ++j)
                    tmp[j] = T[nloc * 130 + 2 * (c * 8 + j) + bsel];
                const int kt = kt0 + (c >> 2);
                const int c2 = c & 3;
                const int ks = c2 >> 1, hv = c2 & 1;
                ushort* dstb = vout + (size_t)bhI * 65536 + (size_t)kt * 2048;
                *(uint4*)(dstb + (ks * 2 + dg) * 512 + (hv * 32 + lid_v) * 8) = *(uint4*)tmp;
            }
        }
    }
}

// ---------------------------------------------------------------------------
// O projection, glds staging, double-buffered, full XOR swizzle.
// BM=BN=64, BK=32, 256 thr. fp32 row-major out[m][n].
// ---------------------------------------------------------------------------
__global__ __launch_bounds__(256)
void proj_o(const ushort* __restrict__ Abf,
            const ushort* __restrict__ Bhg, const ushort* __restrict__ Blg,
            const float* __restrict__ bias, float* __restrict__ outf)
{
    __shared__ ushort smem[2][3 * 2048];   // dbuf x {Ah, Bh, Bl}: 24 KB

    const int fid = blockIdx.x;
    const int nt = (fid & 7) * 2 + ((fid >> 3) & 1);
    const int mt = fid >> 4;
    const int m0 = mt * 64, n0 = nt * 64;

    const int t  = threadIdx.x;
    const int wv = t >> 6, lane = t & 63;
    const int quad = lane >> 4, r = lane & 15;
    const int wm = wv & 1, wn = wv >> 1;
    const int mBase = wm * 32, nBase = wn * 32;

    const int lrow = lane >> 2;
    const int lch  = ((lane & 3) ^ (lrow & 3) ^ ((lrow >> 2) & 3)) * 8;
    const ushort* Asrc  = Abf + (size_t)(m0 + wv * 16 + lrow) * DMODEL + lch;
    const ushort* Bhsrc = Bhg + (size_t)(n0 + wv * 16 + lrow) * DMODEL + lch;
    const ushort* Blsrc = Blg + (size_t)(n0 + wv * 16 + lrow) * DMODEL + lch;

    const int q0x = ((quad ^ (r & 3) ^ ((r >> 2) & 3)) << 3);
    f32x4 acc[2][2];
    #pragma unroll
    for (int i = 0; i < 2; ++i)
        #pragma unroll
        for (int j = 0; j < 2; ++j) acc[i][j] = (f32x4){0.f, 0.f, 0.f, 0.f};

    glds16(Asrc,  smem[0]        + wv * 512);
    glds16(Bhsrc, smem[0] + 2048 + wv * 512);
    glds16(Blsrc, smem[0] + 4096 + wv * 512);

    for (int k = 0; k < 32; ++k) {
        const int cur = k & 1;
        __syncthreads();
        if (k + 1 < 32) {
            const int off = (k + 1) * 32;
            glds16(Asrc  + off, smem[cur ^ 1]        + wv * 512);
            glds16(Bhsrc + off, smem[cur ^ 1] + 2048 + wv * 512);
            glds16(Blsrc + off, smem[cur ^ 1] + 4096 + wv * 512);
        }
        const ushort* Ah = smem[cur];
        const ushort* Bh = smem[cur] + 2048;
        const ushort* Bl = smem[cur] + 4096;
        bf16x8 fa[2], fbh[2], fbl[2];
        #pragma unroll
        for (int i = 0; i < 2; ++i)
            fa[i] = *(const bf16x8*)&Ah[(mBase + i * 16 + r) * 32 + q0x];
        #pragma unroll
        for (int j = 0; j < 2; ++j) {
            fbh[j] = *(const bf16x8*)&Bh[(nBase + j * 16 + r) * 32 + q0x];
            fbl[j] = *(const bf16x8*)&Bl[(nBase + j * 16 + r) * 32 + q0x];
        }
        #pragma unroll
        for (int i = 0; i < 2; ++i)
            #pragma unroll
            for (int j = 0; j < 2; ++j) {
                acc[i][j] = __builtin_amdgcn_mfma_f32_16x16x32_bf16(fa[i], fbh[j], acc[i][j], 0, 0, 0);
                acc[i][j] = __builtin_amdgcn_mfma_f32_16x16x32_bf16(fa[i], fbl[j], acc[i][j], 0, 0, 0);
            }
    }

    const int cn = lane & 15;
    #pragma unroll
    for (int j = 0; j < 2; ++j) {
        const int n = n0 + nBase + j * 16 + cn;
        const float bvv = bias[n];
        #pragma unroll
        for (int i = 0; i < 2; ++i) {
            const int mrow = m0 + mBase + i * 16 + quad * 4;
            #pragma unroll
            for (int g = 0; g < 4; ++g)
                outf[(size_t)(mrow + g) * DMODEL + n] = acc[i][j][g] + bvv;
        }
    }
}

// ---------------------------------------------------------------------------
// MFMA flash attention, swapped-operand layout (zero LDS, zero barriers),
// u=2 query tiles per wave (64 q), software-pipelined, FRAGMENT-LINEAR K/V
// (coalesced base+lane*16B loads). QK chains seeded with a persistent zero
// C-vector. Grid 512, XCD-swizzled.
// ---------------------------------------------------------------------------
__global__ __launch_bounds__(256, 2)
void attn_mfma(const ushort* __restrict__ qhg, const ushort* __restrict__ qlg,
               const ushort* __restrict__ kh, const ushort* __restrict__ vth,
               const float* __restrict__ lwraw, float* __restrict__ part)
{
    const int t    = threadIdx.x;
    const int wv   = t >> 6, lane = t & 63;
    const int half = lane >> 5, lid = lane & 31;

    const int fid  = blockIdx.x;                 // 512 blocks
    const int xcd  = fid & 7, slot = fid >> 3;   // slot in [0,64)
    const int pair = xcd * 16 + (slot >> 2);     // 16 (bh,l) pairs per XCD
    const int qt   = slot & 3;                   // 4 q-tiles of 256 per pair
    const int bh   = pair & 31, l = pair >> 5;
    const int qbase = qt * 256 + wv * 64;        // wave owns 64 queries

    float wl;
    {
        float v[LP1], wm = -3.0e38f;
        #pragma unroll
        for (int i = 0; i < LP1; ++i) { v[i] = lwraw[i]; wm = fmaxf(wm, v[i]); }
        float ws = 0.f;
        #pragma unroll
        for (int i = 0; i < LP1; ++i) { v[i] = __expf(v[i] - wm); ws += v[i]; }
        wl = v[l] / ws;
    }

    // Q fragments (B-frag: lane owns query row qbase+u*32+lid, 8 dims/frag)
    bf16x8 qh[2][4], ql[2][4];
    #pragma unroll
    for (int u = 0; u < 2; ++u) {
        const size_t qoff = ((size_t)bh * S_LEN + qbase + u * 32 + lid) * HDIM + half * 8;
        #pragma unroll
        for (int es = 0; es < 4; ++es) {
            qh[u][es] = *(const bf16x8*)(qhg + qoff + es * 16);
            ql[u][es] = *(const bf16x8*)(qlg + qoff + es * 16);
        }
    }

    f32x16 o[2][2];
    #pragma unroll
    for (int u = 0; u < 2; ++u)
        #pragma unroll
        for (int dg = 0; dg < 2; ++dg)
            #pragma unroll
            for (int i = 0; i < 16; ++i) o[u][dg][i] = 0.f;
    float ls[2] = {0.f, 0.f};

    // persistent zero C-operand: seeds each QK chain, never re-written
    f32x16 zf;
    #pragma unroll
    for (int i = 0; i < 16; ++i) zf[i] = 0.f;

    // fragment-linear bases: every load below is base + lane*16B (coalesced)
    const size_t kvo = (size_t)(l * BHEADS + bh) * S_LEN * HDIM;
    const ushort* kfb = kh  + kvo + (size_t)lane * 8;
    const ushort* vfb = vth + kvo + (size_t)lane * 8;

    // ---- prologue: K(0) -> kb; sa = QK(K(0)); K(1) -> kn ----
    bf16x8 kb[4], kn[4];
    #pragma unroll
    for (int es = 0; es < 4; ++es)
        kb[es] = *(const bf16x8*)(kfb + es * 512);
    #pragma unroll
    for (int es = 0; es < 4; ++es)
        kn[es] = *(const bf16x8*)(kfb + 2048 + es * 512);

    f32x16 sa[2];
    #pragma unroll
    for (int es = 0; es < 4; ++es)
        #pragma unroll
        for (int u = 0; u < 2; ++u) {
            sa[u] = __builtin_amdgcn_mfma_f32_32x32x16_bf16(kb[es], qh[u][es],
                                                            es == 0 ? zf : sa[u], 0, 0, 0);
            sa[u] = __builtin_amdgcn_mfma_f32_32x32x16_bf16(kb[es], ql[u][es], sa[u], 0, 0, 0);
        }

    for (int kt = 0; kt < 32; ++kt) {
        // ---- V(kt) loads: coalesced, issued early, consumed by PV ----
        bf16x8 vb[2][2];
        {
            const ushort* vp = vfb + (size_t)kt * 2048;
            #pragma unroll
            for (int ks = 0; ks < 2; ++ks)
                #pragma unroll
                for (int dg = 0; dg < 2; ++dg)
                    vb[ks][dg] = *(const bf16x8*)(vp + (ks * 2 + dg) * 512);
        }

        // ---- softmax(sa of kt) -> pf[2][2], ls; sa dead afterwards ----
        // sa[u] = S^T[k][q]: lane owns col q, reg r -> k=(r&3)+8*(r>>2)+4*half
        bf16x8 pf[2][2];
        #pragma unroll
        for (int ks = 0; ks < 2; ++ks) {
            #pragma unroll
            for (int u = 0; u < 2; ++u) {
                const float p0 = fast_exp2(sa[u][8 * ks + 0]);
                const float p1 = fast_exp2(sa[u][8 * ks + 1]);
                const float p2 = fast_exp2(sa[u][8 * ks + 2]);
                const float p3 = fast_exp2(sa[u][8 * ks + 3]);
                const float p4 = fast_exp2(sa[u][8 * ks + 4]);
                const float p5 = fast_exp2(sa[u][8 * ks + 5]);
                const float p6 = fast_exp2(sa[u][8 * ks + 6]);
                const float p7 = fast_exp2(sa[u][8 * ks + 7]);
                ls[u] += ((p0 + p1) + (p2 + p3)) + ((p4 + p5) + (p6 + p7));

                // Own regs (local k within the 16-key group):
                //   half=0: a0={0,1} a1={2,3} b0={8,9}  b1={10,11}
                //   half=1: a0={4,5} a1={6,7} b0={12,13} b1={14,15}
                // Lane needs k = half*8 + 0..7 of column q=lid.
                uint a0 = pk_bf16(p0, p1);
                uint a1 = pk_bf16(p2, p3);
                uint b0 = pk_bf16(p4, p5);
                uint b1 = pk_bf16(p6, p7);
                // a[32:63] <- b[0:31]; b[0:31] <- a[32:63]:
                //   a0 -> half0:{0,1}  half1:{8,9}   = W0
                //   b0 -> half0:{4,5}  half1:{12,13} = W2
                permswap(a0, b0);
                permswap(a1, b1);            // a1 = W1, b1 = W3
                union { uint w[4]; bf16x8 v; } pu;
                pu.w[0] = a0; pu.w[1] = a1; pu.w[2] = b0; pu.w[3] = b1;
                pf[ks][u] = pu.v;
            }
        }

        // ---- advance K: kb <- kn, prefetch K(kt+2), coalesced ----
        #pragma unroll
        for (int es = 0; es < 4; ++es) kb[es] = kn[es];
        {
            const ushort* kp = kfb + (size_t)((kt + 2) & 31) * 2048;
            #pragma unroll
            for (int es = 0; es < 4; ++es) kn[es] = *(const bf16x8*)(kp + es * 512);
        }

        // ---- QK(kt+1) -> sa (zf-seeded; kt=31 computes an unused tile) ----
        __builtin_amdgcn_s_setprio(1);
        #pragma unroll
        for (int es = 0; es < 4; ++es)
            #pragma unroll
            for (int u = 0; u < 2; ++u) {
                sa[u] = __builtin_amdgcn_mfma_f32_32x32x16_bf16(kb[es], qh[u][es],
                                                                es == 0 ? zf : sa[u], 0, 0, 0);
                sa[u] = __builtin_amdgcn_mfma_f32_32x32x16_bf16(kb[es], ql[u][es], sa[u], 0, 0, 0);
            }
        __builtin_amdgcn_s_setprio(0);

        // ---- PV(kt): o += V^T(kt) x P^T(kt) ----
        __builtin_amdgcn_s_setprio(1);
        #pragma unroll
        for (int ks = 0; ks < 2; ++ks)
            #pragma unroll
            for (int dg = 0; dg < 2; ++dg)
                #pragma unroll
                for (int u = 0; u < 2; ++u)
                    o[u][dg] = __builtin_amdgcn_mfma_f32_32x32x16_bf16(vb[ks][dg], pf[ks][u], o[u][dg], 0, 0, 0);
        __builtin_amdgcn_s_setprio(0);
    }

    // ---- epilogue: combine half-lane partial sums, scale, store O^T ----
    const int b = bh >> 4, hh = bh & 15;
    #pragma unroll
    for (int u = 0; u < 2; ++u) {
        float lsv = ls[u];
        lsv += __shfl_xor(lsv, 32);
        const float sc = wl / lsv;
        const int q = qbase + u * 32 + lid;
        float* pb = part + (size_t)l * (ROWS_PL * DMODEL)
                  + ((size_t)q * BATCH + b) * DMODEL + hh * HDIM;
        #pragma unroll
        for (int dg = 0; dg < 2; ++dg)
            #pragma unroll
            for (int rq = 0; rq < 4; ++rq) {
                float4 vv;
                vv.x = o[u][dg][rq * 4 + 0] * sc;
                vv.y = o[u][dg][rq * 4 + 1] * sc;
                vv.z = o[u][dg][rq * 4 + 2] * sc;
                vv.w = o[u][dg][rq * 4 + 3] * sc;
                *(float4*)(pb + dg * 32 + rq * 8 + half * 4) = vv;
            }
    }
}

// ---------------------------------------------------------------------------
// Sum the 4 layer partials -> bf16 hi plane for the O projection.
// ---------------------------------------------------------------------------
__global__ __launch_bounds__(256)
void sum_y(const float* __restrict__ part, ushort* __restrict__ YH)
{
    const int i = (blockIdx.x * 256 + threadIdx.x) * 8;
    float acc[8];
    #pragma unroll
    for (int c = 0; c < 2; ++c) {
        float4 s = *(const float4*)(part + i + c * 4);
        #pragma unroll
        for (int l = 1; l < LP1; ++l) {
            const float4 p = *(const float4*)(part + (size_t)l * 2097152 + i + c * 4);
            s.x += p.x; s.y += p.y; s.z += p.z; s.w += p.w;
        }
        acc[c * 4 + 0] = s.x; acc[c * 4 + 1] = s.y;
        acc[c * 4 + 2] = s.z; acc[c * 4 + 3] = s.w;
    }
    uint out[4];
    #pragma unroll
    for (int c = 0; c < 4; ++c) out[c] = pk_bf16(acc[c * 2], acc[c * 2 + 1]);
    *(uint4*)(YH + i) = *(uint4*)out;
}

// ---------------------------------------------------------------------------
extern "C" void kernel_launch(void* const* d_in, const int* in_sizes, int n_in,
                              void* d_out, int out_size, void* d_ws, size_t ws_size,
                              hipStream_t stream) {
    const float* x  = (const float*)d_in[0];
    const float* lo = (const float*)d_in[1];
    const float* Wq = (const float*)d_in[2];
    const float* bq = (const float*)d_in[3];
    const float* Wk = (const float*)d_in[4];
    const float* bk = (const float*)d_in[5];
    const float* Wv = (const float*)d_in[6];
    const float* bv = (const float*)d_in[7];
    const float* Wo = (const float*)d_in[8];
    const float* bo = (const float*)d_in[9];
    const float* lw = (const float*)d_in[10];
    float* out = (float*)d_out;

    char* ws = (char*)d_ws;
    ushort* XsH  = (ushort*)(ws);                          // 16,777,216 B
    ushort* WH   = (ushort*)(ws + 16777216);               //  8,388,608 B
    ushort* WL   = (ushort*)(ws + 25165824);               //  8,388,608 B (Wq/Wo only)
    ushort* qhb  = (ushort*)(ws + 33554432);               //  4,194,304 B
    ushort* qlb  = (ushort*)(ws + 37748736);               //  4,194,304 B
    ushort* khb  = (ushort*)(ws + 41943040);               // 16,777,216 B
    ushort* vthb = (ushort*)(ws + 58720256);               // 16,777,216 B
    float*  part = (float*)(ws + 75497472);                // 33,554,432 B
    ushort* YH   = (ushort*)(ws + 109051904);              //  4,194,304 B
    // total 113,246,208 B

    dim3 blk(256);
    // Xs -> hi plane; Wq/Wo -> hi+lo; Wk/Wv -> hi only
    presplit<<<dim3(3072, 1, 6), blk, 0, stream>>>(x, lo, Wq, Wk, Wv, Wo, XsH, WH, WL);
    // merged Q + KV projections (LPT: KV blocks first, Q blocks in the tail)
    proj_qkv<<<dim3(1024), blk, 0, stream>>>(XsH, WH, WL, bq, bk, bv,
                                             qhb, qlb, khb, vthb);
    // attention: 512 XCD-swizzled blocks -> per-layer fp32 partials
    attn_mfma<<<dim3(512), blk, 0, stream>>>(qhb, qlb, khb, vthb, lw, part);
    // reduce 4 partials -> bf16 hi plane
    sum_y<<<dim3(1024), blk, 0, stream>>>(part, YH);
    // output projection (glds dbuf)
    proj_o<<<dim3(512), blk, 0, stream>>>(YH, WH + 3145728, WL + 3145728, bo, out);
}